// Round 1
// baseline (1545.781 us; speedup 1.0000x reference)
//
#include <hip/hip_runtime.h>
#include <math.h>

// ---------------------------------------------------------------------------
// NetVLAD on gfx950: conv3x3 -> BN+ReLU -> conv3x3 -> L2norm -> 1x1 assign
// -> softmax -> VLAD aggregation -> intra + global L2 norm.
// Convs: implicit-GEMM with v_mfma_f32_16x16x32_bf16, 128x128 tile, BK=32.
//   K order: k = tap*512 + ci  (tap = (dh+1)*3 + (dw+1)), so each BK=32 slice
//   lies in a single tap -> one boundary predicate per staging thread.
// Fragment layouts (HW-verified per guide):
//   A/B operand: idx = lane&15, k = (lane>>4)*8 + j  (8 contiguous bf16)
//   C/D:         col = lane&15, row = (lane>>4)*4 + reg
// ---------------------------------------------------------------------------

typedef __bf16 bf16x8 __attribute__((ext_vector_type(8)));
typedef float f32x4 __attribute__((ext_vector_type(4)));

// ---------------- conv as implicit GEMM ------------------------------------
// grid: (128 pixel-tiles, 4 o-tiles); block 256 = 4 waves (2x2)
// MODE 0: out = bf16 h, apply BN scale/shift + ReLU
// MODE 1: out = fp32 x_enc (to d_out), accumulate per-pixel sum(x^2) atomics
template <int MODE, typename TIN>
__global__ __launch_bounds__(256) void conv_gemm(
    const TIN* __restrict__ in, const __bf16* __restrict__ wt,
    const float* __restrict__ scale, const float* __restrict__ shift,
    void* __restrict__ outp, float* __restrict__ pixnorm) {
  __shared__ __align__(16) __bf16 Wl[128 * 32];
  __shared__ __align__(16) __bf16 Pl[128 * 32];

  const int t = threadIdx.x;
  const int bx = blockIdx.x;  // pixel tile
  const int oT = blockIdx.y;  // output-channel tile
  const int lane = t & 63, wid = t >> 6;
  const int l16 = lane & 15, q = lane >> 4;
  const int wrow = wid >> 1, wcol = wid & 1;

  // staging assignment: row (o or m) = t&127, half (which 16 of BK=32) = t>>7
  const int sl = t & 127;
  const int half = t >> 7;

  const int m_g = bx * 128 + sl;  // 128 pixels per tile, all within one image
  const int n_img = m_g >> 10;
  const int pix = m_g & 1023;
  const int h = pix >> 5, w = pix & 31;
  const TIN* inbase = in + (size_t)n_img * (512 * 1024);
  const __bf16* wbase = wt + (size_t)(oT * 128 + sl) * 4608 + half * 16;

  f32x4 acc[4][4];
#pragma unroll
  for (int i = 0; i < 4; ++i)
#pragma unroll
    for (int j = 0; j < 4; ++j) acc[i][j] = (f32x4){0.f, 0.f, 0.f, 0.f};

  for (int kt = 0; kt < 144; ++kt) {
    // ---- stage weights: 16 bf16 per thread, contiguous
    {
      const __bf16* src = wbase + kt * 32;
      uint4 a0 = *(const uint4*)src;
      uint4 a1 = *(const uint4*)(src + 8);
      *(uint4*)&Wl[sl * 32 + half * 16] = a0;
      *(uint4*)&Wl[sl * 32 + half * 16 + 8] = a1;
    }
    // ---- stage im2col pixels: 16 channels, one tap, one predicate
    {
      const int tap = kt >> 4;
      const int ci0 = ((kt & 15) << 5) + half * 16;
      const int dh = tap / 3 - 1, dw = tap % 3 - 1;
      const int hs = h + dh, wsx = w + dw;
      const bool valid = ((unsigned)hs < 32u) && ((unsigned)wsx < 32u);
      const TIN* src = inbase + (size_t)ci0 * 1024 + hs * 32 + wsx;
      union {
        __bf16 b[16];
        uint4 u[2];
      } tmp;
#pragma unroll
      for (int j = 0; j < 16; ++j) {
        float v = valid ? (float)src[j * 1024] : 0.0f;
        tmp.b[j] = (__bf16)v;
      }
      *(uint4*)&Pl[sl * 32 + half * 16] = tmp.u[0];
      *(uint4*)&Pl[sl * 32 + half * 16 + 8] = tmp.u[1];
    }
    __syncthreads();

    bf16x8 aw[4], bp[4];
#pragma unroll
    for (int i = 0; i < 4; ++i)
      aw[i] = *(const bf16x8*)&Wl[(wrow * 64 + i * 16 + l16) * 32 + q * 8];
#pragma unroll
    for (int i = 0; i < 4; ++i)
      bp[i] = *(const bf16x8*)&Pl[(wcol * 64 + i * 16 + l16) * 32 + q * 8];
#pragma unroll
    for (int mt = 0; mt < 4; ++mt)
#pragma unroll
      for (int nt = 0; nt < 4; ++nt)
        acc[mt][nt] = __builtin_amdgcn_mfma_f32_16x16x32_bf16(
            aw[mt], bp[nt], acc[mt][nt], 0, 0, 0);
    __syncthreads();
  }

  // ---- epilogue ----
  __bf16* outh = (__bf16*)outp;
  float* outf = (float*)outp;
#pragma unroll
  for (int nt = 0; nt < 4; ++nt) {
    const int m_l = wcol * 64 + nt * 16 + l16;
    const int mg2 = bx * 128 + m_l;
    const int n2 = mg2 >> 10, pix2 = mg2 & 1023;
    float psum = 0.f;
#pragma unroll
    for (int mt = 0; mt < 4; ++mt) {
      const int ob = oT * 128 + wrow * 64 + mt * 16 + q * 4;
      f32x4 v = acc[mt][nt];
      if (MODE == 0) {
        const f32x4 sc = *(const f32x4*)&scale[ob];
        const f32x4 sh = *(const f32x4*)&shift[ob];
#pragma unroll
        for (int r = 0; r < 4; ++r) {
          float val = fmaxf(v[r] * sc[r] + sh[r], 0.f);
          outh[(size_t)(n2 * 512 + ob + r) * 1024 + pix2] = (__bf16)val;
        }
      } else {
#pragma unroll
        for (int r = 0; r < 4; ++r) {
          float val = v[r];
          outf[(size_t)(n2 * 512 + ob + r) * 1024 + pix2] = val;
          psum += val * val;
        }
      }
    }
    if (MODE == 1) {
      psum += __shfl_xor(psum, 16);
      psum += __shfl_xor(psum, 32);
      if (lane < 16) atomicAdd(&pixnorm[n2 * 1024 + pix2], psum);
    }
  }
}

// ---------------- soft-assign + softmax ------------------------------------
// one thread per pixel; 64 logits in registers; weights via wave-uniform reads
__global__ __launch_bounds__(256) void assign_softmax(
    const float* __restrict__ xe, const float* __restrict__ wat,
    const float* __restrict__ pixnorm, float* __restrict__ saP,
    float* __restrict__ S) {
  __shared__ float Sl[64];
  const int t = threadIdx.x;
  const int pg = blockIdx.x * 256 + t;
  const int n = pg >> 10, pix = pg & 1023;
  if (t < 64) Sl[t] = 0.f;
  __syncthreads();

  float acc[64];
#pragma unroll
  for (int k = 0; k < 64; ++k) acc[k] = 0.f;
  const float* xb = xe + (size_t)n * 512 * 1024 + pix;
#pragma unroll 2
  for (int c = 0; c < 512; ++c) {
    float xv = xb[c * 1024];
#pragma unroll
    for (int k = 0; k < 64; ++k) acc[k] = fmaf(xv, wat[c * 64 + k], acc[k]);
  }
  const float rn = 1.0f / fmaxf(sqrtf(pixnorm[n * 1024 + pix]), 1e-12f);
  float mx = -3.4e38f;
#pragma unroll
  for (int k = 0; k < 64; ++k) {
    acc[k] *= rn;
    mx = fmaxf(mx, acc[k]);
  }
  float sum = 0.f;
#pragma unroll
  for (int k = 0; k < 64; ++k) {
    acc[k] = __expf(acc[k] - mx);
    sum += acc[k];
  }
  const float inv = 1.0f / sum;
#pragma unroll
  for (int k = 0; k < 64; ++k) {
    float sa = acc[k] * inv;
    atomicAdd(&Sl[k], sa);
    saP[(size_t)(n * 64 + k) * 1024 + pix] = sa * rn;  // fold rnorm for GEMM
  }
  __syncthreads();
  if (t < 64) atomicAdd(&S[n * 64 + t], Sl[t]);
}

// ---------------- VLAD aggregation: vraw[n,k,c] = sum_l sa'[k,l]*xe[c,l] ----
// grid (8 c-chunks, 16 n); block 256; LDS-tiled fp32
__global__ __launch_bounds__(256) void vlad_gemm(const float* __restrict__ saP,
                                                 const float* __restrict__ xe,
                                                 float* __restrict__ vraw) {
  __shared__ float sa_l[64 * 64];
  __shared__ float x_l[64 * 65];
  const int t = threadIdx.x;
  const int cq = blockIdx.x, n = blockIdx.y;
  const int c0 = cq * 64;
  const int lane = t & 63, grp = t >> 6;
  float acc[16];
#pragma unroll
  for (int j = 0; j < 16; ++j) acc[j] = 0.f;

  for (int lc = 0; lc < 16; ++lc) {
    const int l0 = lc * 64;
#pragma unroll
    for (int i = 0; i < 16; ++i) {
      const int row = grp + 4 * i;
      sa_l[row * 64 + lane] = saP[(size_t)(n * 64 + row) * 1024 + l0 + lane];
      x_l[row * 65 + lane] = xe[(size_t)(n * 512 + c0 + row) * 1024 + l0 + lane];
    }
    __syncthreads();
#pragma unroll 4
    for (int l = 0; l < 64; ++l) {
      const float xv = x_l[lane * 65 + l];
#pragma unroll
      for (int j = 0; j < 16; ++j)
        acc[j] = fmaf(sa_l[(grp * 16 + j) * 64 + l], xv, acc[j]);
    }
    __syncthreads();
  }
#pragma unroll
  for (int j = 0; j < 16; ++j)
    vraw[(size_t)(n * 64 + grp * 16 + j) * 512 + c0 + lane] = acc[j];
}

// ---------------- intra-norm (per n,k over c) + global ss accumulation -----
__global__ __launch_bounds__(64) void intra_norm(float* __restrict__ vraw,
                                                 const float* __restrict__ S,
                                                 const float* __restrict__ cent,
                                                 float* __restrict__ gss) {
  const int b = blockIdx.x;  // n*64 + k
  const int n = b >> 6, k = b & 63;
  const int lane = threadIdx.x;
  const float s = S[b];
  float v[8];
  float ss = 0.f;
#pragma unroll
  for (int j = 0; j < 8; ++j) {
    const int c = lane * 8 + j;
    float val = vraw[(size_t)b * 512 + c] - s * cent[k * 512 + c];
    v[j] = val;
    ss += val * val;
  }
#pragma unroll
  for (int off = 1; off < 64; off <<= 1) ss += __shfl_xor(ss, off);
  const float rn = 1.0f / fmaxf(sqrtf(ss), 1e-12f);
#pragma unroll
  for (int j = 0; j < 8; ++j) vraw[(size_t)b * 512 + lane * 8 + j] = v[j] * rn;
  if (lane == 0) atomicAdd(&gss[n], ss * rn * rn);
}

// ---------------- final global norm ----------------------------------------
__global__ __launch_bounds__(256) void finalize(const float* __restrict__ vraw,
                                                const float* __restrict__ gss,
                                                float* __restrict__ out) {
  const int id = blockIdx.x * 256 + threadIdx.x;
  const int n = id >> 15;
  out[id] = vraw[id] * (1.0f / fmaxf(sqrtf(gss[n]), 1e-12f));
}

// ---------------- prep kernels ---------------------------------------------
__global__ void zero_ws(float* p, int count) {
  int i = blockIdx.x * 256 + threadIdx.x;
  if (i < count) p[i] = 0.f;
}

// OIHW fp32 -> [o][tap*512+ci] bf16
__global__ void wt_prep(const float* __restrict__ w, __bf16* __restrict__ wt) {
  const int o = blockIdx.y;
  const int idk = blockIdx.x * 256 + threadIdx.x;  // 0..4607
  const int tap = idk >> 9, ci = idk & 511;
  wt[(size_t)o * 4608 + idk] = (__bf16)w[(size_t)o * 4608 + ci * 9 + tap];
}

__global__ void misc_prep(const float* g, const float* b, const float* m,
                          const float* v, const float* wA, float* scale,
                          float* shift, float* wat) {
  const int i = blockIdx.x * 256 + threadIdx.x;
  if (i < 512) {
    float sc = g[i] / sqrtf(v[i] + 1e-5f);
    scale[i] = sc;
    shift[i] = b[i] - m[i] * sc;
  } else if (i < 512 + 64 * 512) {
    const int id = i - 512;
    const int c = id >> 6, k = id & 63;
    wat[c * 64 + k] = wA[k * 512 + c];
  }
}

// ---------------------------------------------------------------------------
extern "C" void kernel_launch(void* const* d_in, const int* in_sizes, int n_in,
                              void* d_out, int out_size, void* d_ws,
                              size_t ws_size, hipStream_t stream) {
  const float* x = (const float*)d_in[0];
  const float* w1 = (const float*)d_in[1];
  const float* gam = (const float*)d_in[2];
  const float* bet = (const float*)d_in[3];
  const float* mean = (const float*)d_in[4];
  const float* var = (const float*)d_in[5];
  const float* w2 = (const float*)d_in[6];
  const float* wA = (const float*)d_in[7];
  const float* cent = (const float*)d_in[8];
  float* out = (float*)d_out;

  char* ws = (char*)d_ws;
  __bf16* Wt1 = (__bf16*)(ws + 0);
  __bf16* Wt2 = (__bf16*)(ws + 4718592);
  __bf16* hbf = (__bf16*)(ws + 9437184);      // 16*512*1024 bf16
  float* scale = (float*)(ws + 26214400);     // 512
  float* shift = (float*)(ws + 26216448);     // 512
  float* wat = (float*)(ws + 26218496);       // 512*64
  float* pixnorm = (float*)(ws + 26349568);   // 16*1024
  float* S = (float*)(ws + 26415104);         // 16*64
  float* gss = (float*)(ws + 26419200);       // 16
  float* saP = (float*)(ws + 26419264);       // 16*64*1024
  float* vraw = (float*)(ws + 30613568);      // 16*64*512

  float* xenc = out + 524288;  // output 1 region (vlad is output 0)

  // zero pixnorm+S+gss (contiguous, 17424 floats) — ws is poisoned each call
  zero_ws<<<69, 256, 0, stream>>>(pixnorm, 17424);
  misc_prep<<<130, 256, 0, stream>>>(gam, bet, mean, var, wA, scale, shift, wat);
  wt_prep<<<dim3(18, 512), 256, 0, stream>>>(w1, Wt1);
  wt_prep<<<dim3(18, 512), 256, 0, stream>>>(w2, Wt2);

  conv_gemm<0, float><<<dim3(128, 4), 256, 0, stream>>>(x, Wt1, scale, shift,
                                                        hbf, nullptr);
  conv_gemm<1, __bf16><<<dim3(128, 4), 256, 0, stream>>>(
      hbf, Wt2, nullptr, nullptr, xenc, pixnorm);

  assign_softmax<<<64, 256, 0, stream>>>(xenc, wat, pixnorm, saP, S);
  vlad_gemm<<<dim3(8, 16), 256, 0, stream>>>(saP, xenc, vraw);
  intra_norm<<<1024, 64, 0, stream>>>(vraw, S, cent, gss);
  finalize<<<2048, 256, 0, stream>>>(vraw, gss, out);
}

// Round 2
// 748.712 us; speedup vs baseline: 2.0646x; 2.0646x over previous
//
#include <hip/hip_runtime.h>
#include <math.h>

// ---------------------------------------------------------------------------
// NetVLAD on gfx950.
// Convs = implicit GEMM, v_mfma_f32_16x16x32_bf16, 128x128 tile, BK=32.
// Inputs pre-transformed to padded NHWC bf16 [16][34][34][512] -> no boundary
// predicates; K-slice (tap, ci0..ci0+31) is 64 contiguous bytes per pixel.
// Staging via global_load_lds width=16 (lane-contiguous LDS image).
// Bank-conflict fix: XOR chunk swizzle cpos = c ^ ((row>>1)&3) applied on the
// GLOBAL source address (prepacked for weights) -> fragment ds_read_b128 is
// exactly 2-way (free), writes conflict-free.
// Fragment layouts (HW-verified): A/B: idx=lane&15, k=(lane>>4)*8+j;
// C/D: col=lane&15, row=(lane>>4)*4+reg.
// ---------------------------------------------------------------------------

typedef __bf16 bf16x8 __attribute__((ext_vector_type(8)));
typedef float f32x4 __attribute__((ext_vector_type(4)));

#define GLDS16(gp, lp)                                                  \
  __builtin_amdgcn_global_load_lds(                                     \
      (const __attribute__((address_space(1))) void*)(gp),              \
      (__attribute__((address_space(3))) void*)(lp), 16, 0, 0)

// ---------------- conv as implicit GEMM ------------------------------------
// grid (128 pixel-tiles, 4 o-tiles), block 256 = 4 waves (2x2)
// MODE 0: BN+ReLU -> hpad bf16 NHWC (padded).  MODE 1: fp32 NCHW x_enc +
// per-pixel sum(x^2) atomics.
template <int MODE>
__global__ __launch_bounds__(256) void conv_gemm(
    const __bf16* __restrict__ in,  // padded NHWC bf16 [16][34][34][512]
    const __bf16* __restrict__ wt,  // prepacked+swizzled [512][144*32]
    const float* __restrict__ scale, const float* __restrict__ shift,
    void* __restrict__ outp, float* __restrict__ pixnorm) {
  __shared__ __align__(16) __bf16 Wl[128 * 32];
  __shared__ __align__(16) __bf16 Pl[128 * 32];

  const int t = threadIdx.x;
  const int bx = blockIdx.x, oT = blockIdx.y;
  const int lane = t & 63, wid = t >> 6;
  const int l16 = lane & 15, q = lane >> 4;
  const int wrow = wid >> 1, wcol = wid & 1;

  // ---- staging descriptors: 2 chunks per thread (j0 = t, j1 = t + 256)
  const int j0 = t, j1 = t + 256;
  const __bf16* ws0 = wt + (size_t)(oT * 128 + (j0 >> 2)) * 4608 + (j0 & 3) * 8;
  const __bf16* ws1 = wt + (size_t)(oT * 128 + (j1 >> 2)) * 4608 + (j1 & 3) * 8;

  const int r0 = j0 >> 2, cg0 = (j0 & 3) ^ ((j0 >> 3) & 3);
  const int r1 = j1 >> 2, cg1 = (j1 & 3) ^ ((j1 >> 3) & 3);
  const int pg0 = bx * 128 + r0, pg1 = bx * 128 + r1;
  const __bf16* ps0 =
      in + ((size_t)(pg0 >> 10) * 1156 + (((pg0 & 1023) >> 5) + 1) * 34 +
            ((pg0 & 31) + 1)) * 512 + cg0 * 8;
  const __bf16* ps1 =
      in + ((size_t)(pg1 >> 10) * 1156 + (((pg1 & 1023) >> 5) + 1) * 34 +
            ((pg1 & 31) + 1)) * 512 + cg1 * 8;

  // wave-uniform LDS bases (bf16 elements): chunk_base*8
  const int ldsb0 = wid * 512;
  const int ldsb1 = 2048 + wid * 512;

  // ---- fragment read addresses (constant over K)
  const int sw = (q ^ ((l16 >> 1) & 3)) * 8;
  const int aoff = (wrow * 64 + l16) * 32 + sw;
  const int boff = (wcol * 64 + l16) * 32 + sw;

  f32x4 acc[4][4];
#pragma unroll
  for (int i = 0; i < 4; ++i)
#pragma unroll
    for (int j = 0; j < 4; ++j) acc[i][j] = (f32x4){0.f, 0.f, 0.f, 0.f};

#pragma unroll 1
  for (int tap = 0; tap < 9; ++tap) {
    const int dh = tap / 3, dw = tap - dh * 3;
    const int doffs = ((dh - 1) * 34 + (dw - 1)) * 512;
    const __bf16* p0 = ps0 + doffs;
    const __bf16* p1 = ps1 + doffs;
    const __bf16* w0 = ws0 + tap * 512;
    const __bf16* w1 = ws1 + tap * 512;
#pragma unroll 1
    for (int kc = 0; kc < 16; ++kc) {
      GLDS16(w0 + kc * 32, Wl + ldsb0);
      GLDS16(w1 + kc * 32, Wl + ldsb1);
      GLDS16(p0 + kc * 32, Pl + ldsb0);
      GLDS16(p1 + kc * 32, Pl + ldsb1);
      __syncthreads();

      bf16x8 aw[4], bp[4];
#pragma unroll
      for (int i = 0; i < 4; ++i) aw[i] = *(const bf16x8*)&Wl[aoff + i * 512];
#pragma unroll
      for (int i = 0; i < 4; ++i) bp[i] = *(const bf16x8*)&Pl[boff + i * 512];
#pragma unroll
      for (int mt = 0; mt < 4; ++mt)
#pragma unroll
        for (int nt = 0; nt < 4; ++nt)
          acc[mt][nt] = __builtin_amdgcn_mfma_f32_16x16x32_bf16(
              aw[mt], bp[nt], acc[mt][nt], 0, 0, 0);
      __syncthreads();
    }
  }

  // ---- epilogue ----
#pragma unroll
  for (int nt = 0; nt < 4; ++nt) {
    const int m_l = wcol * 64 + nt * 16 + l16;
    const int mg2 = bx * 128 + m_l;
    const int n2 = mg2 >> 10, pix2 = mg2 & 1023;
    float psum = 0.f;
#pragma unroll
    for (int mt = 0; mt < 4; ++mt) {
      const int ob = oT * 128 + wrow * 64 + mt * 16 + q * 4;
      f32x4 v = acc[mt][nt];
      if (MODE == 0) {
        const f32x4 sc = *(const f32x4*)&scale[ob];
        const f32x4 sh = *(const f32x4*)&shift[ob];
        union {
          __bf16 b[4];
          uint2 u;
        } pk;
#pragma unroll
        for (int r = 0; r < 4; ++r)
          pk.b[r] = (__bf16)fmaxf(v[r] * sc[r] + sh[r], 0.f);
        __bf16* dst = (__bf16*)outp +
                      ((size_t)n2 * 1156 + ((pix2 >> 5) + 1) * 34 +
                       ((pix2 & 31) + 1)) * 512 + ob;
        *(uint2*)dst = pk.u;
      } else {
        float* outf = (float*)outp;
#pragma unroll
        for (int r = 0; r < 4; ++r) {
          float val = v[r];
          outf[(size_t)(n2 * 512 + ob + r) * 1024 + pix2] = val;
          psum += val * val;
        }
      }
    }
    if (MODE == 1) {
      psum += __shfl_xor(psum, 16);
      psum += __shfl_xor(psum, 32);
      if (lane < 16) atomicAdd(&pixnorm[n2 * 1024 + pix2], psum);
    }
  }
}

// ---------------- x (fp32 NCHW) -> xpad (bf16 NHWC padded) -----------------
// grid 512 = (n,h); 256 threads: w = t&31, cgroup = t>>5 (64 ch each)
__global__ __launch_bounds__(256) void xform(const float* __restrict__ x,
                                             __bf16* __restrict__ xpad) {
  const int n = blockIdx.x >> 5, h = blockIdx.x & 31;
  const int t = threadIdx.x;
  const int w = t & 31, cg = t >> 5;
  const float* src = x + ((size_t)n * 512 + cg * 64) * 1024 + h * 32 + w;
  __bf16* dst =
      xpad + ((size_t)n * 1156 + (h + 1) * 34 + (w + 1)) * 512 + cg * 64;
  union {
    __bf16 b[8];
    uint4 u;
  } pk;
#pragma unroll 1
  for (int jj = 0; jj < 8; ++jj) {
#pragma unroll
    for (int j = 0; j < 8; ++j) pk.b[j] = (__bf16)src[(jj * 8 + j) * 1024];
    *(uint4*)(dst + jj * 8) = pk.u;
  }
}

// ---------------- soft-assign + softmax ------------------------------------
// grid 256 blocks; block = 64 pixels x 4 channel-splits (128 ch each)
__global__ __launch_bounds__(256) void assign_softmax(
    const float* __restrict__ xe, const float* __restrict__ wat,
    const float* __restrict__ pixnorm, float* __restrict__ saP,
    float* __restrict__ S) {
  __shared__ float Acc[64 * 65];
  __shared__ float Mx[64], Inv[64], Rn[64];
  const int t = threadIdx.x;
  const int split = t >> 6, p = t & 63;
  const int pg = blockIdx.x * 64 + p;
  const int n = pg >> 10, pix = pg & 1023;

  float acc[64];
#pragma unroll
  for (int k = 0; k < 64; ++k) acc[k] = 0.f;
  const float* xb = xe + (size_t)n * 524288 + pix;
  const int c0 = split * 128;
#pragma unroll 1
  for (int c = c0; c < c0 + 128; ++c) {
    float xv = xb[(size_t)c * 1024];
#pragma unroll
    for (int k = 0; k < 64; ++k) acc[k] = fmaf(xv, wat[c * 64 + k], acc[k]);
  }
  // merge 4 splits into LDS
  for (int s = 0; s < 4; ++s) {
    if (split == s) {
      if (s == 0) {
#pragma unroll
        for (int k = 0; k < 64; ++k) Acc[p * 65 + k] = acc[k];
      } else {
#pragma unroll
        for (int k = 0; k < 64; ++k) Acc[p * 65 + k] += acc[k];
      }
    }
    __syncthreads();
  }
  if (t < 64) {
    const float rn = 1.0f / fmaxf(sqrtf(pixnorm[n * 1024 + pix]), 1e-12f);
    float m = -3.4e38f;
#pragma unroll
    for (int k = 0; k < 64; ++k) m = fmaxf(m, Acc[p * 65 + k]);
    float sum = 0.f;
#pragma unroll
    for (int k = 0; k < 64; ++k) sum += __expf((Acc[p * 65 + k] - m) * rn);
    Mx[p] = m;
    Inv[p] = 1.0f / sum;
    Rn[p] = rn;
  }
  __syncthreads();
  const float rn = Rn[p], m = Mx[p], inv = Inv[p];
#pragma unroll 1
  for (int j = 0; j < 16; ++j) {
    const int k = split * 16 + j;
    float sa = __expf((Acc[p * 65 + k] - m) * rn) * inv;
    saP[(size_t)(n * 64 + k) * 1024 + pix] = sa * rn;
    float ssum = sa;
#pragma unroll
    for (int off = 1; off < 64; off <<= 1) ssum += __shfl_xor(ssum, off);
    if (p == 0) atomicAdd(&S[n * 64 + k], ssum);
  }
}

// ---------------- VLAD aggregation -----------------------------------------
__global__ __launch_bounds__(256) void vlad_gemm(const float* __restrict__ saP,
                                                 const float* __restrict__ xe,
                                                 float* __restrict__ vraw) {
  __shared__ float sa_l[64 * 64];
  __shared__ float x_l[64 * 65];
  const int t = threadIdx.x;
  const int cq = blockIdx.x, n = blockIdx.y;
  const int c0 = cq * 64;
  const int lane = t & 63, grp = t >> 6;
  float acc[16];
#pragma unroll
  for (int j = 0; j < 16; ++j) acc[j] = 0.f;

  for (int lc = 0; lc < 16; ++lc) {
    const int l0 = lc * 64;
#pragma unroll
    for (int i = 0; i < 16; ++i) {
      const int row = grp + 4 * i;
      sa_l[row * 64 + lane] = saP[(size_t)(n * 64 + row) * 1024 + l0 + lane];
      x_l[row * 65 + lane] = xe[(size_t)(n * 512 + c0 + row) * 1024 + l0 + lane];
    }
    __syncthreads();
#pragma unroll 4
    for (int l = 0; l < 64; ++l) {
      const float xv = x_l[lane * 65 + l];
#pragma unroll
      for (int j = 0; j < 16; ++j)
        acc[j] = fmaf(sa_l[(grp * 16 + j) * 64 + l], xv, acc[j]);
    }
    __syncthreads();
  }
#pragma unroll
  for (int j = 0; j < 16; ++j)
    vraw[(size_t)(n * 64 + grp * 16 + j) * 512 + c0 + lane] = acc[j];
}

// ---------------- intra-norm + global ss -----------------------------------
__global__ __launch_bounds__(64) void intra_norm(float* __restrict__ vraw,
                                                 const float* __restrict__ S,
                                                 const float* __restrict__ cent,
                                                 float* __restrict__ gss) {
  const int b = blockIdx.x;
  const int n = b >> 6, k = b & 63;
  const int lane = threadIdx.x;
  const float s = S[b];
  float v[8];
  float ss = 0.f;
#pragma unroll
  for (int j = 0; j < 8; ++j) {
    const int c = lane * 8 + j;
    float val = vraw[(size_t)b * 512 + c] - s * cent[k * 512 + c];
    v[j] = val;
    ss += val * val;
  }
#pragma unroll
  for (int off = 1; off < 64; off <<= 1) ss += __shfl_xor(ss, off);
  const float rn = 1.0f / fmaxf(sqrtf(ss), 1e-12f);
#pragma unroll
  for (int j = 0; j < 8; ++j) vraw[(size_t)b * 512 + lane * 8 + j] = v[j] * rn;
  if (lane == 0) atomicAdd(&gss[n], ss * rn * rn);
}

__global__ __launch_bounds__(256) void finalize(const float* __restrict__ vraw,
                                                const float* __restrict__ gss,
                                                float* __restrict__ out) {
  const int id = blockIdx.x * 256 + threadIdx.x;
  const int n = id >> 15;
  out[id] = vraw[id] * (1.0f / fmaxf(sqrtf(gss[n]), 1e-12f));
}

// ---------------- prep -----------------------------------------------------
__global__ void zero16(uint4* p, int count16) {
  int i = blockIdx.x * 256 + threadIdx.x;
  if (i < count16) p[i] = (uint4){0u, 0u, 0u, 0u};
}

__global__ void zero_ws(float* p, int count) {
  int i = blockIdx.x * 256 + threadIdx.x;
  if (i < count) p[i] = 0.f;
}

// OIHW fp32 -> [o][kt*32 + cpos*8 + e] bf16 with chunk swizzle baked in
__global__ void wt_prep(const float* __restrict__ w, __bf16* __restrict__ wt) {
  const int o = blockIdx.y;
  const int idk = blockIdx.x * 256 + threadIdx.x;  // 0..4607
  const int kt = idk >> 5, cpos = (idk >> 3) & 3, e = idk & 7;
  const int c = cpos ^ ((o >> 1) & 3);
  const int k2 = kt * 32 + c * 8 + e;
  const int tap = k2 >> 9, ci = k2 & 511;
  wt[(size_t)o * 4608 + idk] = (__bf16)w[(size_t)o * 4608 + ci * 9 + tap];
}

__global__ void misc_prep(const float* g, const float* b, const float* m,
                          const float* v, const float* wA, float* scale,
                          float* shift, float* wat) {
  const int i = blockIdx.x * 256 + threadIdx.x;
  if (i < 512) {
    float sc = g[i] / sqrtf(v[i] + 1e-5f);
    scale[i] = sc;
    shift[i] = b[i] - m[i] * sc;
  } else if (i < 512 + 64 * 512) {
    const int id = i - 512;
    const int c = id >> 6, k = id & 63;
    wat[c * 64 + k] = wA[k * 512 + c];
  }
}

// ---------------------------------------------------------------------------
extern "C" void kernel_launch(void* const* d_in, const int* in_sizes, int n_in,
                              void* d_out, int out_size, void* d_ws,
                              size_t ws_size, hipStream_t stream) {
  const float* x = (const float*)d_in[0];
  const float* w1 = (const float*)d_in[1];
  const float* gam = (const float*)d_in[2];
  const float* bet = (const float*)d_in[3];
  const float* mean = (const float*)d_in[4];
  const float* var = (const float*)d_in[5];
  const float* w2 = (const float*)d_in[6];
  const float* wA = (const float*)d_in[7];
  const float* cent = (const float*)d_in[8];
  float* out = (float*)d_out;

  char* ws = (char*)d_ws;
  __bf16* Wt1 = (__bf16*)(ws + 0);            // 4,718,592
  __bf16* Wt2 = (__bf16*)(ws + 4718592);      // 4,718,592
  __bf16* xpad = (__bf16*)(ws + 9437184);     // 18,939,904 (dead after conv1)
  float* saP = (float*)(ws + 9437184);        // alias: 4,194,304
  float* vraw = (float*)(ws + 13631488);      // alias: 2,097,152
  __bf16* hpad = (__bf16*)(ws + 28377088);    // 18,939,904
  float* scale = (float*)(ws + 47316992);     // 512
  float* shift = (float*)(ws + 47319040);     // 512
  float* wat = (float*)(ws + 47321088);       // 32768
  float* pixnorm = (float*)(ws + 47452160);   // 16384
  float* S = (float*)(ws + 47517696);         // 1024
  float* gss = (float*)(ws + 47521792);       // 16

  float* xenc = out + 524288;  // output 1 (x_enc, fp32 NCHW)

  // zero padded buffers (xpad..hpad contiguous: 37,879,808 B = 2,367,488 x16)
  zero16<<<9248, 256, 0, stream>>>((uint4*)(ws + 9437184), 2367488);
  zero_ws<<<69, 256, 0, stream>>>(pixnorm, 17424);
  misc_prep<<<130, 256, 0, stream>>>(gam, bet, mean, var, wA, scale, shift, wat);
  wt_prep<<<dim3(18, 512), 256, 0, stream>>>(w1, Wt1);
  wt_prep<<<dim3(18, 512), 256, 0, stream>>>(w2, Wt2);
  xform<<<512, 256, 0, stream>>>(x, xpad);

  conv_gemm<0><<<dim3(128, 4), 256, 0, stream>>>(xpad, Wt1, scale, shift, hpad,
                                                 nullptr);
  conv_gemm<1><<<dim3(128, 4), 256, 0, stream>>>(hpad, Wt2, nullptr, nullptr,
                                                 xenc, pixnorm);

  assign_softmax<<<256, 256, 0, stream>>>(xenc, wat, pixnorm, saP, S);
  vlad_gemm<<<dim3(8, 16), 256, 0, stream>>>(saP, xenc, vraw);
  intra_norm<<<1024, 64, 0, stream>>>(vraw, S, cent, gss);
  finalize<<<2048, 256, 0, stream>>>(vraw, gss, out);
}

// Round 3
// 527.265 us; speedup vs baseline: 2.9317x; 1.4200x over previous
//
#include <hip/hip_runtime.h>
#include <math.h>

// ---------------------------------------------------------------------------
// NetVLAD on gfx950.
// Convs = implicit GEMM, v_mfma_f32_16x16x32_bf16, 128x128 tile, BK=32,
// padded NHWC bf16 inputs, global_load_lds staging, XOR chunk swizzle.
// VLAD = bf16 MFMA GEMM per image (M=64 clusters, N=512 ch, K=1024 pixels),
// 4-way K-split, partials summed in intra_norm.
// Fragment layouts (HW-verified): A/B: idx=lane&15, k=(lane>>4)*8+j;
// C/D: col=lane&15, row=(lane>>4)*4+reg.
// ---------------------------------------------------------------------------

typedef __bf16 bf16x8 __attribute__((ext_vector_type(8)));
typedef float f32x4 __attribute__((ext_vector_type(4)));

#define GLDS16(gp, lp)                                                  \
  __builtin_amdgcn_global_load_lds(                                     \
      (const __attribute__((address_space(1))) void*)(gp),              \
      (__attribute__((address_space(3))) void*)(lp), 16, 0, 0)

// ---------------- conv as implicit GEMM ------------------------------------
// grid (128 pixel-tiles, 4 o-tiles), block 256 = 4 waves (2x2)
// MODE 0: BN+ReLU -> hpad bf16 NHWC (padded).
// MODE 1: fp32 NCHW x_enc + bf16 NCHW copy + per-pixel sum(x^2) atomics.
template <int MODE>
__global__ __launch_bounds__(256) void conv_gemm(
    const __bf16* __restrict__ in,  // padded NHWC bf16 [16][34][34][512]
    const __bf16* __restrict__ wt,  // prepacked+swizzled [512][144*32]
    const float* __restrict__ scale, const float* __restrict__ shift,
    void* __restrict__ outp, __bf16* __restrict__ xeb,
    float* __restrict__ pixnorm) {
  __shared__ __align__(16) __bf16 Wl[128 * 32];
  __shared__ __align__(16) __bf16 Pl[128 * 32];

  const int t = threadIdx.x;
  const int bx = blockIdx.x, oT = blockIdx.y;
  const int lane = t & 63, wid = t >> 6;
  const int l16 = lane & 15, q = lane >> 4;
  const int wrow = wid >> 1, wcol = wid & 1;

  const int j0 = t, j1 = t + 256;
  const __bf16* ws0 = wt + (size_t)(oT * 128 + (j0 >> 2)) * 4608 + (j0 & 3) * 8;
  const __bf16* ws1 = wt + (size_t)(oT * 128 + (j1 >> 2)) * 4608 + (j1 & 3) * 8;

  const int r0 = j0 >> 2, cg0 = (j0 & 3) ^ ((j0 >> 3) & 3);
  const int r1 = j1 >> 2, cg1 = (j1 & 3) ^ ((j1 >> 3) & 3);
  const int pg0 = bx * 128 + r0, pg1 = bx * 128 + r1;
  const __bf16* ps0 =
      in + ((size_t)(pg0 >> 10) * 1156 + (((pg0 & 1023) >> 5) + 1) * 34 +
            ((pg0 & 31) + 1)) * 512 + cg0 * 8;
  const __bf16* ps1 =
      in + ((size_t)(pg1 >> 10) * 1156 + (((pg1 & 1023) >> 5) + 1) * 34 +
            ((pg1 & 31) + 1)) * 512 + cg1 * 8;

  const int ldsb0 = wid * 512;
  const int ldsb1 = 2048 + wid * 512;

  const int sw = (q ^ ((l16 >> 1) & 3)) * 8;
  const int aoff = (wrow * 64 + l16) * 32 + sw;
  const int boff = (wcol * 64 + l16) * 32 + sw;

  f32x4 acc[4][4];
#pragma unroll
  for (int i = 0; i < 4; ++i)
#pragma unroll
    for (int j = 0; j < 4; ++j) acc[i][j] = (f32x4){0.f, 0.f, 0.f, 0.f};

#pragma unroll 1
  for (int tap = 0; tap < 9; ++tap) {
    const int dh = tap / 3, dw = tap - dh * 3;
    const int doffs = ((dh - 1) * 34 + (dw - 1)) * 512;
    const __bf16* p0 = ps0 + doffs;
    const __bf16* p1 = ps1 + doffs;
    const __bf16* w0 = ws0 + tap * 512;
    const __bf16* w1 = ws1 + tap * 512;
#pragma unroll 1
    for (int kc = 0; kc < 16; ++kc) {
      GLDS16(w0 + kc * 32, Wl + ldsb0);
      GLDS16(w1 + kc * 32, Wl + ldsb1);
      GLDS16(p0 + kc * 32, Pl + ldsb0);
      GLDS16(p1 + kc * 32, Pl + ldsb1);
      __syncthreads();

      bf16x8 aw[4], bp[4];
#pragma unroll
      for (int i = 0; i < 4; ++i) aw[i] = *(const bf16x8*)&Wl[aoff + i * 512];
#pragma unroll
      for (int i = 0; i < 4; ++i) bp[i] = *(const bf16x8*)&Pl[boff + i * 512];
#pragma unroll
      for (int mt = 0; mt < 4; ++mt)
#pragma unroll
        for (int nt = 0; nt < 4; ++nt)
          acc[mt][nt] = __builtin_amdgcn_mfma_f32_16x16x32_bf16(
              aw[mt], bp[nt], acc[mt][nt], 0, 0, 0);
      __syncthreads();
    }
  }

  // ---- epilogue ----
#pragma unroll
  for (int nt = 0; nt < 4; ++nt) {
    const int m_l = wcol * 64 + nt * 16 + l16;
    const int mg2 = bx * 128 + m_l;
    const int n2 = mg2 >> 10, pix2 = mg2 & 1023;
    float psum = 0.f;
#pragma unroll
    for (int mt = 0; mt < 4; ++mt) {
      const int ob = oT * 128 + wrow * 64 + mt * 16 + q * 4;
      f32x4 v = acc[mt][nt];
      if (MODE == 0) {
        const f32x4 sc = *(const f32x4*)&scale[ob];
        const f32x4 sh = *(const f32x4*)&shift[ob];
        union {
          __bf16 b[4];
          uint2 u;
        } pk;
#pragma unroll
        for (int r = 0; r < 4; ++r)
          pk.b[r] = (__bf16)fmaxf(v[r] * sc[r] + sh[r], 0.f);
        __bf16* dst = (__bf16*)outp +
                      ((size_t)n2 * 1156 + ((pix2 >> 5) + 1) * 34 +
                       ((pix2 & 31) + 1)) * 512 + ob;
        *(uint2*)dst = pk.u;
      } else {
        float* outf = (float*)outp;
#pragma unroll
        for (int r = 0; r < 4; ++r) {
          float val = v[r];
          const size_t idx = (size_t)(n2 * 512 + ob + r) * 1024 + pix2;
          outf[idx] = val;
          xeb[idx] = (__bf16)val;
          psum += val * val;
        }
      }
    }
    if (MODE == 1) {
      psum += __shfl_xor(psum, 16);
      psum += __shfl_xor(psum, 32);
      if (lane < 16) atomicAdd(&pixnorm[n2 * 1024 + pix2], psum);
    }
  }
}

// ---------------- x (fp32 NCHW) -> xpad (bf16 NHWC padded) -----------------
__global__ __launch_bounds__(256) void xform(const float* __restrict__ x,
                                             __bf16* __restrict__ xpad) {
  const int n = blockIdx.x >> 5, h = blockIdx.x & 31;
  const int t = threadIdx.x;
  const int w = t & 31, cg = t >> 5;
  const float* src = x + ((size_t)n * 512 + cg * 64) * 1024 + h * 32 + w;
  __bf16* dst =
      xpad + ((size_t)n * 1156 + (h + 1) * 34 + (w + 1)) * 512 + cg * 64;
  union {
    __bf16 b[8];
    uint4 u;
  } pk;
#pragma unroll 1
  for (int jj = 0; jj < 8; ++jj) {
#pragma unroll
    for (int j = 0; j < 8; ++j) pk.b[j] = (__bf16)src[(jj * 8 + j) * 1024];
    *(uint4*)(dst + jj * 8) = pk.u;
  }
}

// ---------------- soft-assign + softmax ------------------------------------
// grid 256 blocks; block = 64 pixels x 4 channel-splits (128 ch each)
__global__ __launch_bounds__(256) void assign_softmax(
    const float* __restrict__ xe, const float* __restrict__ wat,
    const float* __restrict__ pixnorm, __bf16* __restrict__ saPb,
    float* __restrict__ S) {
  __shared__ float Acc[64 * 65];
  __shared__ float Mx[64], Inv[64], Rn[64];
  const int t = threadIdx.x;
  const int split = t >> 6, p = t & 63;
  const int pg = blockIdx.x * 64 + p;
  const int n = pg >> 10, pix = pg & 1023;

  float acc[64];
#pragma unroll
  for (int k = 0; k < 64; ++k) acc[k] = 0.f;
  const float* xb = xe + (size_t)n * 524288 + pix;
  const int c0 = split * 128;
#pragma unroll 1
  for (int c = c0; c < c0 + 128; ++c) {
    float xv = xb[(size_t)c * 1024];
#pragma unroll
    for (int k = 0; k < 64; ++k) acc[k] = fmaf(xv, wat[c * 64 + k], acc[k]);
  }
  for (int s = 0; s < 4; ++s) {
    if (split == s) {
      if (s == 0) {
#pragma unroll
        for (int k = 0; k < 64; ++k) Acc[p * 65 + k] = acc[k];
      } else {
#pragma unroll
        for (int k = 0; k < 64; ++k) Acc[p * 65 + k] += acc[k];
      }
    }
    __syncthreads();
  }
  if (t < 64) {
    const float rn = 1.0f / fmaxf(sqrtf(pixnorm[n * 1024 + pix]), 1e-12f);
    float m = -3.4e38f;
#pragma unroll
    for (int k = 0; k < 64; ++k) m = fmaxf(m, Acc[p * 65 + k]);
    float sum = 0.f;
#pragma unroll
    for (int k = 0; k < 64; ++k) sum += __expf((Acc[p * 65 + k] - m) * rn);
    Mx[p] = m;
    Inv[p] = 1.0f / sum;
    Rn[p] = rn;
  }
  __syncthreads();
  const float rn = Rn[p], m = Mx[p], inv = Inv[p];
#pragma unroll 1
  for (int j = 0; j < 16; ++j) {
    const int k = split * 16 + j;
    float sa = __expf((Acc[p * 65 + k] - m) * rn) * inv;
    saPb[(size_t)(n * 64 + k) * 1024 + pix] = (__bf16)(sa * rn);
    float ssum = sa;
#pragma unroll
    for (int off = 1; off < 64; off <<= 1) ssum += __shfl_xor(ssum, off);
    if (p == 0) atomicAdd(&S[n * 64 + k], ssum);
  }
}

// ---------------- VLAD aggregation: bf16 MFMA GEMM -------------------------
// vpart[ks][n][k][c] = sum_{l in chunk ks} saPb[n,k,l]*xeb[n,c,l]
// grid (4 c-tiles, 16 n, 4 k-splits); block 256 = 4 waves (2x2)
__global__ __launch_bounds__(256) void vlad_gemm(
    const __bf16* __restrict__ saPb, const __bf16* __restrict__ xeb,
    float* __restrict__ vpart) {
  __shared__ __align__(16) __bf16 Al[64 * 32];
  __shared__ __align__(16) __bf16 Bl[128 * 32];

  const int t = threadIdx.x;
  const int cT = blockIdx.x, n = blockIdx.y, ks = blockIdx.z;
  const int lane = t & 63, wid = t >> 6;
  const int l16 = lane & 15, q = lane >> 4;
  const int wrow = wid >> 1, wcol = wid & 1;

  // A staging: chunk j=t -> row=t>>2 (64 rows), cpos=t&3
  const int ar = t >> 2, acp = t & 3;
  const __bf16* asrc = saPb + (size_t)n * 65536 + (size_t)ar * 1024 + ks * 256 +
                       (acp ^ ((ar >> 1) & 3)) * 8;
  // B staging: chunks j0=t, j1=t+256 -> rows 0..127
  const int br0 = t >> 2, bcp0 = t & 3;
  const int br1 = (t + 256) >> 2, bcp1 = t & 3;
  const __bf16* bsrc0 = xeb + (size_t)n * 524288 +
                        (size_t)(cT * 128 + br0) * 1024 + ks * 256 +
                        (bcp0 ^ ((br0 >> 1) & 3)) * 8;
  const __bf16* bsrc1 = xeb + (size_t)n * 524288 +
                        (size_t)(cT * 128 + br1) * 1024 + ks * 256 +
                        (bcp1 ^ ((br1 >> 1) & 3)) * 8;

  const int ldsb = wid * 512;

  const int sw = (q ^ ((l16 >> 1) & 3)) * 8;

  f32x4 acc[2][4];
#pragma unroll
  for (int i = 0; i < 2; ++i)
#pragma unroll
    for (int j = 0; j < 4; ++j) acc[i][j] = (f32x4){0.f, 0.f, 0.f, 0.f};

#pragma unroll 1
  for (int kc = 0; kc < 8; ++kc) {
    GLDS16(asrc + kc * 32, Al + ldsb);
    GLDS16(bsrc0 + kc * 32, Bl + ldsb);
    GLDS16(bsrc1 + kc * 32, Bl + 2048 + ldsb);
    __syncthreads();

    bf16x8 af[2], bf[4];
#pragma unroll
    for (int i = 0; i < 2; ++i)
      af[i] = *(const bf16x8*)&Al[(wrow * 32 + i * 16 + l16) * 32 + sw];
#pragma unroll
    for (int i = 0; i < 4; ++i)
      bf[i] = *(const bf16x8*)&Bl[(wcol * 64 + i * 16 + l16) * 32 + sw];
#pragma unroll
    for (int mt = 0; mt < 2; ++mt)
#pragma unroll
      for (int nt = 0; nt < 4; ++nt)
        acc[mt][nt] = __builtin_amdgcn_mfma_f32_16x16x32_bf16(
            af[mt], bf[nt], acc[mt][nt], 0, 0, 0);
    __syncthreads();
  }

  float* vp = vpart + (size_t)(ks * 16 + n) * 32768;
#pragma unroll
  for (int mt = 0; mt < 2; ++mt) {
    const int krow = wrow * 32 + mt * 16 + q * 4;
#pragma unroll
    for (int nt = 0; nt < 4; ++nt) {
      const int ccol = cT * 128 + wcol * 64 + nt * 16 + l16;
#pragma unroll
      for (int r = 0; r < 4; ++r)
        vp[(size_t)(krow + r) * 512 + ccol] = acc[mt][nt][r];
    }
  }
}

// ---------------- intra-norm (sums 4 K-split partials) ---------------------
__global__ __launch_bounds__(64) void intra_norm(float* __restrict__ vraw,
                                                 const float* __restrict__ vpart,
                                                 const float* __restrict__ S,
                                                 const float* __restrict__ cent,
                                                 float* __restrict__ gss) {
  const int b = blockIdx.x;  // n*64 + k
  const int n = b >> 6, k = b & 63;
  const int lane = threadIdx.x;
  const float s = S[b];
  float v[8];
  float ss = 0.f;
#pragma unroll
  for (int j = 0; j < 8; ++j) {
    const int c = lane * 8 + j;
    const size_t off = (size_t)b * 512 + c;
    float val = vpart[off] + vpart[524288 + off] + vpart[2 * 524288 + off] +
                vpart[3 * 524288 + off] - s * cent[k * 512 + c];
    v[j] = val;
    ss += val * val;
  }
#pragma unroll
  for (int off = 1; off < 64; off <<= 1) ss += __shfl_xor(ss, off);
  const float rn = 1.0f / fmaxf(sqrtf(ss), 1e-12f);
#pragma unroll
  for (int j = 0; j < 8; ++j) vraw[(size_t)b * 512 + lane * 8 + j] = v[j] * rn;
  if (lane == 0) atomicAdd(&gss[n], ss * rn * rn);
}

__global__ __launch_bounds__(256) void finalize(const float* __restrict__ vraw,
                                                const float* __restrict__ gss,
                                                float* __restrict__ out) {
  const int id = blockIdx.x * 256 + threadIdx.x;
  const int n = id >> 15;
  out[id] = vraw[id] * (1.0f / fmaxf(sqrtf(gss[n]), 1e-12f));
}

// ---------------- prep -----------------------------------------------------
__global__ void zero16(uint4* p, int count16) {
  int i = blockIdx.x * 256 + threadIdx.x;
  if (i < count16) p[i] = (uint4){0u, 0u, 0u, 0u};
}

__global__ void zero_ws(float* p, int count) {
  int i = blockIdx.x * 256 + threadIdx.x;
  if (i < count) p[i] = 0.f;
}

// OIHW fp32 -> [o][kt*32 + cpos*8 + e] bf16 with chunk swizzle baked in
__global__ void wt_prep(const float* __restrict__ w, __bf16* __restrict__ wt) {
  const int o = blockIdx.y;
  const int idk = blockIdx.x * 256 + threadIdx.x;  // 0..4607
  const int kt = idk >> 5, cpos = (idk >> 3) & 3, e = idk & 7;
  const int c = cpos ^ ((o >> 1) & 3);
  const int k2 = kt * 32 + c * 8 + e;
  const int tap = k2 >> 9, ci = k2 & 511;
  wt[(size_t)o * 4608 + idk] = (__bf16)w[(size_t)o * 4608 + ci * 9 + tap];
}

__global__ void misc_prep(const float* g, const float* b, const float* m,
                          const float* v, const float* wA, float* scale,
                          float* shift, float* wat) {
  const int i = blockIdx.x * 256 + threadIdx.x;
  if (i < 512) {
    float sc = g[i] / sqrtf(v[i] + 1e-5f);
    scale[i] = sc;
    shift[i] = b[i] - m[i] * sc;
  } else if (i < 512 + 64 * 512) {
    const int id = i - 512;
    const int c = id >> 6, k = id & 63;
    wat[c * 64 + k] = wA[k * 512 + c];
  }
}

// ---------------------------------------------------------------------------
extern "C" void kernel_launch(void* const* d_in, const int* in_sizes, int n_in,
                              void* d_out, int out_size, void* d_ws,
                              size_t ws_size, hipStream_t stream) {
  const float* x = (const float*)d_in[0];
  const float* w1 = (const float*)d_in[1];
  const float* gam = (const float*)d_in[2];
  const float* bet = (const float*)d_in[3];
  const float* mean = (const float*)d_in[4];
  const float* var = (const float*)d_in[5];
  const float* w2 = (const float*)d_in[6];
  const float* wA = (const float*)d_in[7];
  const float* cent = (const float*)d_in[8];
  float* out = (float*)d_out;

  char* ws = (char*)d_ws;
  __bf16* Wt1 = (__bf16*)(ws + 0);            // 4,718,592
  __bf16* Wt2 = (__bf16*)(ws + 4718592);      // 4,718,592
  __bf16* xpad = (__bf16*)(ws + 9437184);     // 18,939,904 (dead after conv1)
  __bf16* xeb = (__bf16*)(ws + 9437184);      // alias: 16,777,216
  __bf16* saPb = (__bf16*)(ws + 26214400);    // alias: 2,097,152
  __bf16* hpad = (__bf16*)(ws + 28377088);    // 18,939,904 (dead after conv2)
  float* vpart = (float*)(ws + 28377088);     // alias: 8,388,608
  float* vraw = (float*)(ws + 36765696);      // alias: 2,097,152
  float* scale = (float*)(ws + 47316992);     // 512
  float* shift = (float*)(ws + 47319040);     // 512
  float* wat = (float*)(ws + 47321088);       // 32768
  float* pixnorm = (float*)(ws + 47452160);   // 16384
  float* S = (float*)(ws + 47517696);         // 1024
  float* gss = (float*)(ws + 47521792);       // 16

  float* xenc = out + 524288;  // output 1 (x_enc, fp32 NCHW)

  // zero padded buffers (xpad..hpad contiguous: 37,879,808 B = 2,367,488 x16)
  zero16<<<9248, 256, 0, stream>>>((uint4*)(ws + 9437184), 2367488);
  zero_ws<<<69, 256, 0, stream>>>(pixnorm, 17424);
  misc_prep<<<130, 256, 0, stream>>>(gam, bet, mean, var, wA, scale, shift, wat);
  wt_prep<<<dim3(18, 512), 256, 0, stream>>>(w1, Wt1);
  wt_prep<<<dim3(18, 512), 256, 0, stream>>>(w2, Wt2);
  xform<<<512, 256, 0, stream>>>(x, xpad);

  conv_gemm<0><<<dim3(128, 4), 256, 0, stream>>>(xpad, Wt1, scale, shift, hpad,
                                                 nullptr, nullptr);
  conv_gemm<1><<<dim3(128, 4), 256, 0, stream>>>(hpad, Wt2, nullptr, nullptr,
                                                 xenc, xeb, pixnorm);

  assign_softmax<<<256, 256, 0, stream>>>(xenc, wat, pixnorm, saPb, S);
  vlad_gemm<<<dim3(4, 16, 4), 256, 0, stream>>>(saPb, xeb, vpart);
  intra_norm<<<1024, 64, 0, stream>>>(vraw, vpart, S, cent, gss);
  finalize<<<2048, 256, 0, stream>>>(vraw, gss, out);
}

// Round 4
// 390.955 us; speedup vs baseline: 3.9539x; 1.3487x over previous
//
#include <hip/hip_runtime.h>
#include <math.h>

// ---------------------------------------------------------------------------
// NetVLAD on gfx950.
// conv1/conv2: implicit GEMM, v_mfma_f32_16x16x32_bf16, 128x128 tile, BK=32,
//   padded NHWC bf16 inputs, global_load_lds staging, XOR chunk swizzle.
// conv2 emits xebT = bf16 [n][pix][c] (c-contiguous).
// expand_x: LDS-transpose xebT -> fp32 NCHW x_enc (output 1) + bf16 xeb
//   [n][c][pix] (pixel-contiguous, for VLAD).
// assign_softmax: MFMA GEMM logits = watb(64k x 512c) * xn, softmax in
//   registers (shfl over quad groups), pixnorm folded in from LDS tiles.
// vlad: bf16 MFMA GEMM (M=64 k, N=512 c, K=1024 pix), 4-way K-split.
// Fragment layouts (HW-verified): A/B: idx=lane&15, k=(lane>>4)*8+j;
// C/D: col=lane&15 (B idx), row=(lane>>4)*4+reg (A idx).
// ---------------------------------------------------------------------------

typedef __bf16 bf16x8 __attribute__((ext_vector_type(8)));
typedef float f32x4 __attribute__((ext_vector_type(4)));

#define GLDS16(gp, lp)                                                  \
  __builtin_amdgcn_global_load_lds(                                     \
      (const __attribute__((address_space(1))) void*)(gp),              \
      (__attribute__((address_space(3))) void*)(lp), 16, 0, 0)

// ---------------- conv as implicit GEMM ------------------------------------
// grid (128 pixel-tiles, 4 o-tiles), block 256 = 4 waves (2x2)
// MODE 0: BN+ReLU -> padded NHWC bf16 (hpad).
// MODE 1: xebT bf16 [n][pix][512] (c-contiguous), no BN.
template <int MODE>
__global__ __launch_bounds__(256) void conv_gemm(
    const __bf16* __restrict__ in,  // padded NHWC bf16 [16][34][34][512]
    const __bf16* __restrict__ wt,  // prepacked+swizzled [512][144*32]
    const float* __restrict__ scale, const float* __restrict__ shift,
    __bf16* __restrict__ outp) {
  __shared__ __align__(16) __bf16 Wl[128 * 32];
  __shared__ __align__(16) __bf16 Pl[128 * 32];

  const int t = threadIdx.x;
  const int bx = blockIdx.x, oT = blockIdx.y;
  const int lane = t & 63, wid = t >> 6;
  const int l16 = lane & 15, q = lane >> 4;
  const int wrow = wid >> 1, wcol = wid & 1;

  const int j0 = t, j1 = t + 256;
  const __bf16* ws0 = wt + (size_t)(oT * 128 + (j0 >> 2)) * 4608 + (j0 & 3) * 8;
  const __bf16* ws1 = wt + (size_t)(oT * 128 + (j1 >> 2)) * 4608 + (j1 & 3) * 8;

  const int r0 = j0 >> 2, cg0 = (j0 & 3) ^ ((j0 >> 3) & 3);
  const int r1 = j1 >> 2, cg1 = (j1 & 3) ^ ((j1 >> 3) & 3);
  const int pg0 = bx * 128 + r0, pg1 = bx * 128 + r1;
  const __bf16* ps0 =
      in + ((size_t)(pg0 >> 10) * 1156 + (((pg0 & 1023) >> 5) + 1) * 34 +
            ((pg0 & 31) + 1)) * 512 + cg0 * 8;
  const __bf16* ps1 =
      in + ((size_t)(pg1 >> 10) * 1156 + (((pg1 & 1023) >> 5) + 1) * 34 +
            ((pg1 & 31) + 1)) * 512 + cg1 * 8;

  const int ldsb0 = wid * 512;
  const int ldsb1 = 2048 + wid * 512;

  const int sw = (q ^ ((l16 >> 1) & 3)) * 8;
  const int aoff = (wrow * 64 + l16) * 32 + sw;
  const int boff = (wcol * 64 + l16) * 32 + sw;

  f32x4 acc[4][4];
#pragma unroll
  for (int i = 0; i < 4; ++i)
#pragma unroll
    for (int j = 0; j < 4; ++j) acc[i][j] = (f32x4){0.f, 0.f, 0.f, 0.f};

#pragma unroll 1
  for (int tap = 0; tap < 9; ++tap) {
    const int dh = tap / 3, dw = tap - dh * 3;
    const int doffs = ((dh - 1) * 34 + (dw - 1)) * 512;
    const __bf16* p0 = ps0 + doffs;
    const __bf16* p1 = ps1 + doffs;
    const __bf16* w0 = ws0 + tap * 512;
    const __bf16* w1 = ws1 + tap * 512;
#pragma unroll 1
    for (int kc = 0; kc < 16; ++kc) {
      GLDS16(w0 + kc * 32, Wl + ldsb0);
      GLDS16(w1 + kc * 32, Wl + ldsb1);
      GLDS16(p0 + kc * 32, Pl + ldsb0);
      GLDS16(p1 + kc * 32, Pl + ldsb1);
      __syncthreads();

      bf16x8 aw[4], bp[4];
#pragma unroll
      for (int i = 0; i < 4; ++i) aw[i] = *(const bf16x8*)&Wl[aoff + i * 512];
#pragma unroll
      for (int i = 0; i < 4; ++i) bp[i] = *(const bf16x8*)&Pl[boff + i * 512];
#pragma unroll
      for (int mt = 0; mt < 4; ++mt)
#pragma unroll
        for (int nt = 0; nt < 4; ++nt)
          acc[mt][nt] = __builtin_amdgcn_mfma_f32_16x16x32_bf16(
              aw[mt], bp[nt], acc[mt][nt], 0, 0, 0);
      __syncthreads();
    }
  }

  // ---- epilogue ----
#pragma unroll
  for (int nt = 0; nt < 4; ++nt) {
    const int m_l = wcol * 64 + nt * 16 + l16;
    const int mg2 = bx * 128 + m_l;
    const int n2 = mg2 >> 10, pix2 = mg2 & 1023;
#pragma unroll
    for (int mt = 0; mt < 4; ++mt) {
      const int ob = oT * 128 + wrow * 64 + mt * 16 + q * 4;
      f32x4 v = acc[mt][nt];
      union {
        __bf16 b[4];
        uint2 u;
      } pk;
      if (MODE == 0) {
        const f32x4 sc = *(const f32x4*)&scale[ob];
        const f32x4 sh = *(const f32x4*)&shift[ob];
#pragma unroll
        for (int r = 0; r < 4; ++r)
          pk.b[r] = (__bf16)fmaxf(v[r] * sc[r] + sh[r], 0.f);
        __bf16* dst = outp +
                      ((size_t)n2 * 1156 + ((pix2 >> 5) + 1) * 34 +
                       ((pix2 & 31) + 1)) * 512 + ob;
        *(uint2*)dst = pk.u;
      } else {
#pragma unroll
        for (int r = 0; r < 4; ++r) pk.b[r] = (__bf16)v[r];
        __bf16* dst = outp + ((size_t)n2 * 1024 + pix2) * 512 + ob;
        *(uint2*)dst = pk.u;
      }
    }
  }
}

// ---------------- x (fp32 NCHW) -> xpad (bf16 NHWC padded) -----------------
__global__ __launch_bounds__(256) void xform(const float* __restrict__ x,
                                             __bf16* __restrict__ xpad) {
  const int n = blockIdx.x >> 5, h = blockIdx.x & 31;
  const int t = threadIdx.x;
  const int w = t & 31, cg = t >> 5;
  const float* src = x + ((size_t)n * 512 + cg * 64) * 1024 + h * 32 + w;
  __bf16* dst =
      xpad + ((size_t)n * 1156 + (h + 1) * 34 + (w + 1)) * 512 + cg * 64;
  union {
    __bf16 b[8];
    uint4 u;
  } pk;
#pragma unroll 1
  for (int jj = 0; jj < 8; ++jj) {
#pragma unroll
    for (int j = 0; j < 8; ++j) pk.b[j] = (__bf16)src[(jj * 8 + j) * 1024];
    *(uint4*)(dst + jj * 8) = pk.u;
  }
}

// ---------------- expand: xebT [pix][c] -> xenc fp32 [c][pix] + xeb bf16 ---
// grid (8 c-chunks, 16 p-tiles, 16 n), 256 thr; LDS 64x64 bf16, XOR swizzle.
__global__ __launch_bounds__(256) void expand_x(const __bf16* __restrict__ xebT,
                                                float* __restrict__ xenc,
                                                __bf16* __restrict__ xeb) {
  __shared__ __align__(16) __bf16 Ll[64 * 64];
  const int t = threadIdx.x;
  const int cc = blockIdx.x, ptile = blockIdx.y, n = blockIdx.z;
  const int p0 = ptile * 64, c0 = cc * 64;
#pragma unroll
  for (int i = 0; i < 2; ++i) {
    const int u = t * 2 + i;
    const int pix = u >> 3, c8 = u & 7;
    uint4 v =
        *(const uint4*)&xebT[((size_t)n * 1024 + p0 + pix) * 512 + c0 + c8 * 8];
    *(uint4*)&Ll[pix * 64 + (c8 ^ (pix & 7)) * 8] = v;
  }
  __syncthreads();
  const int c = t >> 2, g = t & 3;
  union {
    float f[4];
    float4 v;
  } fv[4];
  union {
    __bf16 b[16];
    uint4 u[2];
  } bv;
#pragma unroll
  for (int r = 0; r < 16; ++r) {
    const int pix = g * 16 + r;
    __bf16 b = Ll[pix * 64 + ((c >> 3) ^ (pix & 7)) * 8 + (c & 7)];
    bv.b[r] = b;
    fv[r >> 2].f[r & 3] = (float)b;
  }
  float* fd = xenc + ((size_t)n * 512 + c0 + c) * 1024 + p0 + g * 16;
#pragma unroll
  for (int r = 0; r < 4; ++r) *(float4*)(fd + r * 4) = fv[r].v;
  __bf16* bd = xeb + ((size_t)n * 512 + c0 + c) * 1024 + p0 + g * 16;
  *(uint4*)bd = bv.u[0];
  *(uint4*)(bd + 8) = bv.u[1];
}

// ---------------- soft-assign + softmax (MFMA) -----------------------------
// grid (16 p-tiles of 64, 16 n); block 256 = 4 waves, wave = 16 pix x 64 k.
// K=512 channels, BK=32, global_load_lds + XOR swizzle. pixnorm accumulated
// from the staged LDS tiles during the K-loop; softmax in registers via
// shfl_xor(16/32) across quad groups.
__global__ __launch_bounds__(256) void assign_softmax(
    const __bf16* __restrict__ xebT, const __bf16* __restrict__ watb,
    __bf16* __restrict__ saPb, float* __restrict__ S) {
  __shared__ __align__(16) __bf16 Al[64 * 32];
  __shared__ __align__(16) __bf16 Wlb[64 * 32];
  __shared__ float Sl[64];
  const int t = threadIdx.x;
  const int pt = blockIdx.x, n = blockIdx.y;
  const int lane = t & 63, wid = t >> 6;
  const int l16 = lane & 15, q = lane >> 4;
  if (t < 64) Sl[t] = 0.f;

  const int arow = t >> 2;  // pixel row 0..63
  const __bf16* asrc = xebT + ((size_t)n * 1024 + pt * 64 + arow) * 512 +
                       ((t & 3) ^ ((arow >> 1) & 3)) * 8;
  const __bf16* wsrc = watb + (size_t)(t >> 2) * 512 + (t & 3) * 8;
  const int ldsb = wid * 512;
  const int sw = (q ^ ((l16 >> 1) & 3)) * 8;
  const int pnoff = (t >> 2) * 32 + (t & 3) * 8;

  f32x4 acc[4];
#pragma unroll
  for (int i = 0; i < 4; ++i) acc[i] = (f32x4){0.f, 0.f, 0.f, 0.f};
  float pn = 0.f;

#pragma unroll 1
  for (int kc = 0; kc < 16; ++kc) {
    GLDS16(asrc + kc * 32, Al + ldsb);
    GLDS16(wsrc + kc * 32, Wlb + ldsb);
    __syncthreads();
    {
      bf16x8 v = *(const bf16x8*)&Al[pnoff];
#pragma unroll
      for (int j = 0; j < 8; ++j) {
        float f = (float)v[j];
        pn = fmaf(f, f, pn);
      }
    }
    bf16x8 pf = *(const bf16x8*)&Al[(wid * 16 + l16) * 32 + sw];
    bf16x8 wf[4];
#pragma unroll
    for (int ka = 0; ka < 4; ++ka)
      wf[ka] = *(const bf16x8*)&Wlb[(ka * 16 + l16) * 32 + sw];
#pragma unroll
    for (int ka = 0; ka < 4; ++ka)
      acc[ka] =
          __builtin_amdgcn_mfma_f32_16x16x32_bf16(wf[ka], pf, acc[ka], 0, 0, 0);
    __syncthreads();
  }
  // pixnorm: thread t holds partial for pixel lane>>2; reduce over low 2 bits
  pn += __shfl_xor(pn, 1);
  pn += __shfl_xor(pn, 2);
  // pixel l16 (within wave) has its pn at lane l16*4
  const float rn = 1.0f / fmaxf(sqrtf(__shfl(pn, l16 * 4)), 1e-12f);

  float sc[16];
  float m = -3.4e38f;
#pragma unroll
  for (int ka = 0; ka < 4; ++ka)
#pragma unroll
    for (int r = 0; r < 4; ++r) {
      float v = acc[ka][r] * rn;
      sc[ka * 4 + r] = v;
      m = fmaxf(m, v);
    }
  m = fmaxf(m, __shfl_xor(m, 16));
  m = fmaxf(m, __shfl_xor(m, 32));
  float s = 0.f;
#pragma unroll
  for (int j = 0; j < 16; ++j) {
    sc[j] = __expf(sc[j] - m);
    s += sc[j];
  }
  s += __shfl_xor(s, 16);
  s += __shfl_xor(s, 32);
  const float inv = 1.0f / s;
  const int pixg = pt * 64 + wid * 16 + l16;
#pragma unroll
  for (int j = 0; j < 16; ++j) {
    const int k = (j >> 2) * 16 + q * 4 + (j & 3);
    float sa = sc[j] * inv;
    sc[j] = sa;
    saPb[((size_t)n * 64 + k) * 1024 + pixg] = (__bf16)(sa * rn);
  }
  // S[k]: sum over this wave's 16 pixels (l16 bits = lane bits 0..3)
#pragma unroll
  for (int j = 0; j < 16; ++j) {
    float v = sc[j];
    v += __shfl_xor(v, 1);
    v += __shfl_xor(v, 2);
    v += __shfl_xor(v, 4);
    v += __shfl_xor(v, 8);
    sc[j] = v;
  }
  if (l16 == 0) {
#pragma unroll
    for (int j = 0; j < 16; ++j)
      atomicAdd(&Sl[(j >> 2) * 16 + q * 4 + (j & 3)], sc[j]);
  }
  __syncthreads();
  if (t < 64) atomicAdd(&S[n * 64 + t], Sl[t]);
}

// ---------------- VLAD aggregation: bf16 MFMA GEMM -------------------------
// vpart[ks][n][k][c] = sum_{l in chunk ks} saPb[n,k,l]*xeb[n,c,l]
// grid (4 c-tiles, 16 n, 4 k-splits); block 256 = 4 waves (2x2)
__global__ __launch_bounds__(256) void vlad_gemm(
    const __bf16* __restrict__ saPb, const __bf16* __restrict__ xeb,
    float* __restrict__ vpart) {
  __shared__ __align__(16) __bf16 Al[64 * 32];
  __shared__ __align__(16) __bf16 Bl[128 * 32];

  const int t = threadIdx.x;
  const int cT = blockIdx.x, n = blockIdx.y, ks = blockIdx.z;
  const int lane = t & 63, wid = t >> 6;
  const int l16 = lane & 15, q = lane >> 4;
  const int wrow = wid >> 1, wcol = wid & 1;

  const int ar = t >> 2, acp = t & 3;
  const __bf16* asrc = saPb + (size_t)n * 65536 + (size_t)ar * 1024 + ks * 256 +
                       (acp ^ ((ar >> 1) & 3)) * 8;
  const int br0 = t >> 2, bcp0 = t & 3;
  const int br1 = (t + 256) >> 2, bcp1 = t & 3;
  const __bf16* bsrc0 = xeb + (size_t)n * 524288 +
                        (size_t)(cT * 128 + br0) * 1024 + ks * 256 +
                        (bcp0 ^ ((br0 >> 1) & 3)) * 8;
  const __bf16* bsrc1 = xeb + (size_t)n * 524288 +
                        (size_t)(cT * 128 + br1) * 1024 + ks * 256 +
                        (bcp1 ^ ((br1 >> 1) & 3)) * 8;

  const int ldsb = wid * 512;
  const int sw = (q ^ ((l16 >> 1) & 3)) * 8;

  f32x4 acc[2][4];
#pragma unroll
  for (int i = 0; i < 2; ++i)
#pragma unroll
    for (int j = 0; j < 4; ++j) acc[i][j] = (f32x4){0.f, 0.f, 0.f, 0.f};

#pragma unroll 1
  for (int kc = 0; kc < 8; ++kc) {
    GLDS16(asrc + kc * 32, Al + ldsb);
    GLDS16(bsrc0 + kc * 32, Bl + ldsb);
    GLDS16(bsrc1 + kc * 32, Bl + 2048 + ldsb);
    __syncthreads();

    bf16x8 af[2], bf[4];
#pragma unroll
    for (int i = 0; i < 2; ++i)
      af[i] = *(const bf16x8*)&Al[(wrow * 32 + i * 16 + l16) * 32 + sw];
#pragma unroll
    for (int i = 0; i < 4; ++i)
      bf[i] = *(const bf16x8*)&Bl[(wcol * 64 + i * 16 + l16) * 32 + sw];
#pragma unroll
    for (int mt = 0; mt < 2; ++mt)
#pragma unroll
      for (int nt = 0; nt < 4; ++nt)
        acc[mt][nt] = __builtin_amdgcn_mfma_f32_16x16x32_bf16(
            af[mt], bf[nt], acc[mt][nt], 0, 0, 0);
    __syncthreads();
  }

  float* vp = vpart + (size_t)(ks * 16 + n) * 32768;
#pragma unroll
  for (int mt = 0; mt < 2; ++mt) {
    const int krow = wrow * 32 + mt * 16 + q * 4;
#pragma unroll
    for (int nt = 0; nt < 4; ++nt) {
      const int ccol = cT * 128 + wcol * 64 + nt * 16 + l16;
#pragma unroll
      for (int r = 0; r < 4; ++r)
        vp[(size_t)(krow + r) * 512 + ccol] = acc[mt][nt][r];
    }
  }
}

// ---------------- intra-norm (sums 4 K-split partials) ---------------------
__global__ __launch_bounds__(64) void intra_norm(float* __restrict__ vraw,
                                                 const float* __restrict__ vpart,
                                                 const float* __restrict__ S,
                                                 const float* __restrict__ cent,
                                                 float* __restrict__ gss) {
  const int b = blockIdx.x;  // n*64 + k
  const int n = b >> 6, k = b & 63;
  const int lane = threadIdx.x;
  const float s = S[b];
  float v[8];
  float ss = 0.f;
#pragma unroll
  for (int j = 0; j < 8; ++j) {
    const int c = lane * 8 + j;
    const size_t off = (size_t)b * 512 + c;
    float val = vpart[off] + vpart[524288 + off] + vpart[2 * 524288 + off] +
                vpart[3 * 524288 + off] - s * cent[k * 512 + c];
    v[j] = val;
    ss += val * val;
  }
#pragma unroll
  for (int off = 1; off < 64; off <<= 1) ss += __shfl_xor(ss, off);
  const float rn = 1.0f / fmaxf(sqrtf(ss), 1e-12f);
#pragma unroll
  for (int j = 0; j < 8; ++j) vraw[(size_t)b * 512 + lane * 8 + j] = v[j] * rn;
  if (lane == 0) atomicAdd(&gss[n], ss * rn * rn);
}

__global__ __launch_bounds__(256) void finalize(const float* __restrict__ vraw,
                                                const float* __restrict__ gss,
                                                float* __restrict__ out) {
  const int id = blockIdx.x * 256 + threadIdx.x;
  const int n = id >> 15;
  out[id] = vraw[id] * (1.0f / fmaxf(sqrtf(gss[n]), 1e-12f));
}

// ---------------- prep -----------------------------------------------------
__global__ void zero16(uint4* p, int count16) {
  int i = blockIdx.x * 256 + threadIdx.x;
  if (i < count16) p[i] = (uint4){0u, 0u, 0u, 0u};
}

__global__ void zero_ws(float* p, int count) {
  int i = blockIdx.x * 256 + threadIdx.x;
  if (i < count) p[i] = 0.f;
}

// OIHW fp32 -> [o][kt*32 + cpos*8 + e] bf16 with chunk swizzle baked in
__global__ void wt_prep(const float* __restrict__ w, __bf16* __restrict__ wt) {
  const int o = blockIdx.y;
  const int idk = blockIdx.x * 256 + threadIdx.x;  // 0..4607
  const int kt = idk >> 5, cpos = (idk >> 3) & 3, e = idk & 7;
  const int c = cpos ^ ((o >> 1) & 3);
  const int k2 = kt * 32 + c * 8 + e;
  const int tap = k2 >> 9, ci = k2 & 511;
  wt[(size_t)o * 4608 + idk] = (__bf16)w[(size_t)o * 4608 + ci * 9 + tap];
}

__global__ void misc_prep(const float* g, const float* b, const float* m,
                          const float* v, const float* wA, float* scale,
                          float* shift, __bf16* watb) {
  const int i = blockIdx.x * 256 + threadIdx.x;
  if (i < 512) {
    float sc = g[i] / sqrtf(v[i] + 1e-5f);
    scale[i] = sc;
    shift[i] = b[i] - m[i] * sc;
  } else if (i < 512 + 64 * 512) {
    const int id = i - 512;
    const int k = id >> 9, j = id & 511;
    const int kt = j >> 5, cpos = (j >> 3) & 3, e = j & 7;
    const int c = kt * 32 + (cpos ^ ((k >> 1) & 3)) * 8 + e;
    watb[(size_t)k * 512 + j] = (__bf16)wA[(size_t)k * 512 + c];
  }
}

// ---------------------------------------------------------------------------
extern "C" void kernel_launch(void* const* d_in, const int* in_sizes, int n_in,
                              void* d_out, int out_size, void* d_ws,
                              size_t ws_size, hipStream_t stream) {
  const float* x = (const float*)d_in[0];
  const float* w1 = (const float*)d_in[1];
  const float* gam = (const float*)d_in[2];
  const float* bet = (const float*)d_in[3];
  const float* mean = (const float*)d_in[4];
  const float* var = (const float*)d_in[5];
  const float* w2 = (const float*)d_in[6];
  const float* wA = (const float*)d_in[7];
  const float* cent = (const float*)d_in[8];
  float* out = (float*)d_out;

  char* ws = (char*)d_ws;
  __bf16* Wt1 = (__bf16*)(ws + 0);          // 4,718,592 (dead after conv1)
  __bf16* Wt2 = (__bf16*)(ws + 4718592);    // 4,718,592 (dead after conv2)
  __bf16* xpad = (__bf16*)(ws + 9437184);   // 18,939,904 (dead after conv1)
  __bf16* xebT = (__bf16*)(ws + 9437184);   // alias: 16,777,216 (conv2 out)
  __bf16* saPb = (__bf16*)(ws + 26214400);  // 2,097,152
  __bf16* hpad = (__bf16*)(ws + 28377088);  // 18,939,904 (dead after conv2)
  __bf16* xeb = (__bf16*)(ws + 28377088);   // alias: 16,777,216 (expand out)
  float* vpart = (float*)(ws + 0);          // alias Wt1/2: 8,388,608
  float* vraw = (float*)(ws + 8388608);     // alias: 2,097,152
  float* scale = (float*)(ws + 47316992);   // 2048 B
  float* shift = (float*)(ws + 47319040);   // 2048 B
  __bf16* watb = (__bf16*)(ws + 47321088);  // 65,536 B
  float* S = (float*)(ws + 47386624);       // 4096 B
  float* gss = (float*)(ws + 47390720);     // 64 B

  float* xenc = out + 524288;  // output 1 (x_enc, fp32 NCHW)

  // zero padded regions (xpad..hpad contiguous: 37,879,808 B = 2,367,488 x16)
  zero16<<<9248, 256, 0, stream>>>((uint4*)(ws + 9437184), 2367488);
  zero_ws<<<5, 256, 0, stream>>>(S, 1040);  // S + gss
  misc_prep<<<130, 256, 0, stream>>>(gam, bet, mean, var, wA, scale, shift,
                                     watb);
  wt_prep<<<dim3(18, 512), 256, 0, stream>>>(w1, Wt1);
  wt_prep<<<dim3(18, 512), 256, 0, stream>>>(w2, Wt2);
  xform<<<512, 256, 0, stream>>>(x, xpad);

  conv_gemm<0><<<dim3(128, 4), 256, 0, stream>>>(xpad, Wt1, scale, shift, hpad);
  conv_gemm<1><<<dim3(128, 4), 256, 0, stream>>>(hpad, Wt2, nullptr, nullptr,
                                                 xebT);

  expand_x<<<dim3(8, 16, 16), 256, 0, stream>>>(xebT, xenc, xeb);
  assign_softmax<<<dim3(16, 16), 256, 0, stream>>>(xebT, watb, saPb, S);
  vlad_gemm<<<dim3(4, 16, 4), 256, 0, stream>>>(saPb, xeb, vpart);
  intra_norm<<<1024, 64, 0, stream>>>(vraw, vpart, S, cent, gss);
  finalize<<<2048, 256, 0, stream>>>(vraw, gss, out);
}

// Round 5
// 344.699 us; speedup vs baseline: 4.4844x; 1.1342x over previous
//
#include <hip/hip_runtime.h>
#include <math.h>

// ---------------------------------------------------------------------------
// NetVLAD on gfx950.
// conv1/conv2: implicit GEMM, v_mfma_f32_16x16x32_bf16, 128x128 tile, BK=64
//   (32 MFMA/wave per barrier-pair), padded NHWC bf16 inputs, global_load_lds
//   staging, XOR chunk swizzle over 8 chunks/row (row&7) -> conflict-free
//   b128 reads (verified model: 8-lane phases each hit 8 distinct banks).
// conv2 emits xebT = bf16 [n][pix][c] (c-contiguous).
// expand_x: LDS-transpose xebT -> fp32 NCHW x_enc (output 1) + bf16 xeb.
// assign_softmax: MFMA GEMM logits = watb(64k x 512c) * xn, softmax in regs.
// vlad: bf16 MFMA GEMM (M=64 k, N=512 c, K=1024 pix), 4-way K-split.
// Fragment layouts (HW-verified): A/B: idx=lane&15, k=(lane>>4)*8+j;
// C/D: col=lane&15 (B idx), row=(lane>>4)*4+reg (A idx).
// ---------------------------------------------------------------------------

typedef __bf16 bf16x8 __attribute__((ext_vector_type(8)));
typedef float f32x4 __attribute__((ext_vector_type(4)));

#define GLDS16(gp, lp)                                                  \
  __builtin_amdgcn_global_load_lds(                                     \
      (const __attribute__((address_space(1))) void*)(gp),              \
      (__attribute__((address_space(3))) void*)(lp), 16, 0, 0)

// ---------------- conv as implicit GEMM, BK=64 -----------------------------
// grid (128 pixel-tiles, 4 o-tiles), block 256 = 4 waves (2x2)
// MODE 0: BN+ReLU -> padded NHWC bf16 (hpad).
// MODE 1: xebT bf16 [n][pix][512] (c-contiguous), no BN.
template <int MODE>
__global__ __launch_bounds__(256) void conv_gemm(
    const __bf16* __restrict__ in,  // padded NHWC bf16 [16][34][34][512]
    const __bf16* __restrict__ wt,  // prepacked+swizzled [512][72*64]
    const float* __restrict__ scale, const float* __restrict__ shift,
    __bf16* __restrict__ outp) {
  __shared__ __align__(16) __bf16 Wl[128 * 64];
  __shared__ __align__(16) __bf16 Pl[128 * 64];

  const int t = threadIdx.x;
  const int bx = blockIdx.x, oT = blockIdx.y;
  const int lane = t & 63, wid = t >> 6;
  const int l16 = lane & 15, q = lane >> 4;
  const int wrow = wid >> 1, wcol = wid & 1;

  // staging: thread t stages chunks j = t + 256*i; row=(t>>3)+32i, phys=t&7.
  // W prepacked in phys order; P logical chunk = (t&7) ^ ((t>>3)&7).
  const int srow = t >> 3;
  const int sp = t & 7;
  const int slog = sp ^ (srow & 7);

  const __bf16* wsrc[4];
  const __bf16* psrc[4];
#pragma unroll
  for (int i = 0; i < 4; ++i) {
    wsrc[i] = wt + (size_t)(oT * 128 + 32 * i + srow) * 4608 + sp * 8;
    const int pg = bx * 128 + 32 * i + srow;
    const int n = pg >> 10, pix = pg & 1023;
    psrc[i] = in +
              ((size_t)n * 1156 + ((pix >> 5) + 1) * 34 + ((pix & 31) + 1)) *
                  512 +
              slog * 8;
  }

  // fragment read offsets: row elem base = row*64; phys chunk = c ^ (l16&7)
  const int c0 = (q ^ (l16 & 7)) * 8;
  const int c1 = ((4 + q) ^ (l16 & 7)) * 8;
  int aoff[4], boff[4];
#pragma unroll
  for (int i = 0; i < 4; ++i) {
    aoff[i] = (wrow * 64 + i * 16 + l16) * 64;
    boff[i] = (wcol * 64 + i * 16 + l16) * 64;
  }

  f32x4 acc[4][4];
#pragma unroll
  for (int i = 0; i < 4; ++i)
#pragma unroll
    for (int j = 0; j < 4; ++j) acc[i][j] = (f32x4){0.f, 0.f, 0.f, 0.f};

#pragma unroll 1
  for (int tap = 0; tap < 9; ++tap) {
    const int dh = tap / 3, dw = tap - dh * 3;
    const int doffs = ((dh - 1) * 34 + (dw - 1)) * 512;
    const int woffs = tap * 512;
#pragma unroll 1
    for (int kc = 0; kc < 8; ++kc) {
#pragma unroll
      for (int i = 0; i < 4; ++i)
        GLDS16(wsrc[i] + woffs + kc * 64, Wl + i * 2048 + wid * 512);
#pragma unroll
      for (int i = 0; i < 4; ++i)
        GLDS16(psrc[i] + doffs + kc * 64, Pl + i * 2048 + wid * 512);
      __syncthreads();

      bf16x8 aw[4][2], bp[4][2];
#pragma unroll
      for (int i = 0; i < 4; ++i) {
        aw[i][0] = *(const bf16x8*)&Wl[aoff[i] + c0];
        aw[i][1] = *(const bf16x8*)&Wl[aoff[i] + c1];
      }
#pragma unroll
      for (int i = 0; i < 4; ++i) {
        bp[i][0] = *(const bf16x8*)&Pl[boff[i] + c0];
        bp[i][1] = *(const bf16x8*)&Pl[boff[i] + c1];
      }
#pragma unroll
      for (int kh = 0; kh < 2; ++kh)
#pragma unroll
        for (int mt = 0; mt < 4; ++mt)
#pragma unroll
          for (int nt = 0; nt < 4; ++nt)
            acc[mt][nt] = __builtin_amdgcn_mfma_f32_16x16x32_bf16(
                aw[mt][kh], bp[nt][kh], acc[mt][nt], 0, 0, 0);
      __syncthreads();
    }
  }

  // ---- epilogue ----
#pragma unroll
  for (int nt = 0; nt < 4; ++nt) {
    const int m_l = wcol * 64 + nt * 16 + l16;
    const int mg2 = bx * 128 + m_l;
    const int n2 = mg2 >> 10, pix2 = mg2 & 1023;
#pragma unroll
    for (int mt = 0; mt < 4; ++mt) {
      const int ob = oT * 128 + wrow * 64 + mt * 16 + q * 4;
      f32x4 v = acc[mt][nt];
      union {
        __bf16 b[4];
        uint2 u;
      } pk;
      if (MODE == 0) {
        const f32x4 sc = *(const f32x4*)&scale[ob];
        const f32x4 sh = *(const f32x4*)&shift[ob];
#pragma unroll
        for (int r = 0; r < 4; ++r)
          pk.b[r] = (__bf16)fmaxf(v[r] * sc[r] + sh[r], 0.f);
        __bf16* dst = outp +
                      ((size_t)n2 * 1156 + ((pix2 >> 5) + 1) * 34 +
                       ((pix2 & 31) + 1)) * 512 + ob;
        *(uint2*)dst = pk.u;
      } else {
#pragma unroll
        for (int r = 0; r < 4; ++r) pk.b[r] = (__bf16)v[r];
        __bf16* dst = outp + ((size_t)n2 * 1024 + pix2) * 512 + ob;
        *(uint2*)dst = pk.u;
      }
    }
  }
}

// ---------------- x (fp32 NCHW) -> xpad (bf16 NHWC padded) -----------------
__global__ __launch_bounds__(256) void xform(const float* __restrict__ x,
                                             __bf16* __restrict__ xpad) {
  const int n = blockIdx.x >> 5, h = blockIdx.x & 31;
  const int t = threadIdx.x;
  const int w = t & 31, cg = t >> 5;
  const float* src = x + ((size_t)n * 512 + cg * 64) * 1024 + h * 32 + w;
  __bf16* dst =
      xpad + ((size_t)n * 1156 + (h + 1) * 34 + (w + 1)) * 512 + cg * 64;
  union {
    __bf16 b[8];
    uint4 u;
  } pk;
#pragma unroll 1
  for (int jj = 0; jj < 8; ++jj) {
#pragma unroll
    for (int j = 0; j < 8; ++j) pk.b[j] = (__bf16)src[(jj * 8 + j) * 1024];
    *(uint4*)(dst + jj * 8) = pk.u;
  }
}

// ---------------- expand: xebT [pix][c] -> xenc fp32 [c][pix] + xeb bf16 ---
__global__ __launch_bounds__(256) void expand_x(const __bf16* __restrict__ xebT,
                                                float* __restrict__ xenc,
                                                __bf16* __restrict__ xeb) {
  __shared__ __align__(16) __bf16 Ll[64 * 64];
  const int t = threadIdx.x;
  const int cc = blockIdx.x, ptile = blockIdx.y, n = blockIdx.z;
  const int p0 = ptile * 64, c0 = cc * 64;
#pragma unroll
  for (int i = 0; i < 2; ++i) {
    const int u = t * 2 + i;
    const int pix = u >> 3, c8 = u & 7;
    uint4 v =
        *(const uint4*)&xebT[((size_t)n * 1024 + p0 + pix) * 512 + c0 + c8 * 8];
    *(uint4*)&Ll[pix * 64 + (c8 ^ (pix & 7)) * 8] = v;
  }
  __syncthreads();
  const int c = t >> 2, g = t & 3;
  union {
    float f[4];
    float4 v;
  } fv[4];
  union {
    __bf16 b[16];
    uint4 u[2];
  } bv;
#pragma unroll
  for (int r = 0; r < 16; ++r) {
    const int pix = g * 16 + r;
    __bf16 b = Ll[pix * 64 + ((c >> 3) ^ (pix & 7)) * 8 + (c & 7)];
    bv.b[r] = b;
    fv[r >> 2].f[r & 3] = (float)b;
  }
  float* fd = xenc + ((size_t)n * 512 + c0 + c) * 1024 + p0 + g * 16;
#pragma unroll
  for (int r = 0; r < 4; ++r) *(float4*)(fd + r * 4) = fv[r].v;
  __bf16* bd = xeb + ((size_t)n * 512 + c0 + c) * 1024 + p0 + g * 16;
  *(uint4*)bd = bv.u[0];
  *(uint4*)(bd + 8) = bv.u[1];
}

// ---------------- soft-assign + softmax (MFMA) -----------------------------
__global__ __launch_bounds__(256) void assign_softmax(
    const __bf16* __restrict__ xebT, const __bf16* __restrict__ watb,
    __bf16* __restrict__ saPb, float* __restrict__ S) {
  __shared__ __align__(16) __bf16 Al[64 * 32];
  __shared__ __align__(16) __bf16 Wlb[64 * 32];
  __shared__ float Sl[64];
  const int t = threadIdx.x;
  const int pt = blockIdx.x, n = blockIdx.y;
  const int lane = t & 63, wid = t >> 6;
  const int l16 = lane & 15, q = lane >> 4;
  if (t < 64) Sl[t] = 0.f;

  const int arow = t >> 2;  // pixel row 0..63
  const __bf16* asrc = xebT + ((size_t)n * 1024 + pt * 64 + arow) * 512 +
                       ((t & 3) ^ ((arow >> 1) & 3)) * 8;
  const __bf16* wsrc = watb + (size_t)(t >> 2) * 512 + (t & 3) * 8;
  const int ldsb = wid * 512;
  const int sw = (q ^ ((l16 >> 1) & 3)) * 8;
  const int pnoff = (t >> 2) * 32 + (t & 3) * 8;

  f32x4 acc[4];
#pragma unroll
  for (int i = 0; i < 4; ++i) acc[i] = (f32x4){0.f, 0.f, 0.f, 0.f};
  float pn = 0.f;

#pragma unroll 1
  for (int kc = 0; kc < 16; ++kc) {
    GLDS16(asrc + kc * 32, Al + ldsb);
    GLDS16(wsrc + kc * 32, Wlb + ldsb);
    __syncthreads();
    {
      bf16x8 v = *(const bf16x8*)&Al[pnoff];
#pragma unroll
      for (int j = 0; j < 8; ++j) {
        float f = (float)v[j];
        pn = fmaf(f, f, pn);
      }
    }
    bf16x8 pf = *(const bf16x8*)&Al[(wid * 16 + l16) * 32 + sw];
    bf16x8 wf[4];
#pragma unroll
    for (int ka = 0; ka < 4; ++ka)
      wf[ka] = *(const bf16x8*)&Wlb[(ka * 16 + l16) * 32 + sw];
#pragma unroll
    for (int ka = 0; ka < 4; ++ka)
      acc[ka] =
          __builtin_amdgcn_mfma_f32_16x16x32_bf16(wf[ka], pf, acc[ka], 0, 0, 0);
    __syncthreads();
  }
  pn += __shfl_xor(pn, 1);
  pn += __shfl_xor(pn, 2);
  const float rn = 1.0f / fmaxf(sqrtf(__shfl(pn, l16 * 4)), 1e-12f);

  float sc[16];
  float m = -3.4e38f;
#pragma unroll
  for (int ka = 0; ka < 4; ++ka)
#pragma unroll
    for (int r = 0; r < 4; ++r) {
      float v = acc[ka][r] * rn;
      sc[ka * 4 + r] = v;
      m = fmaxf(m, v);
    }
  m = fmaxf(m, __shfl_xor(m, 16));
  m = fmaxf(m, __shfl_xor(m, 32));
  float s = 0.f;
#pragma unroll
  for (int j = 0; j < 16; ++j) {
    sc[j] = __expf(sc[j] - m);
    s += sc[j];
  }
  s += __shfl_xor(s, 16);
  s += __shfl_xor(s, 32);
  const float inv = 1.0f / s;
  const int pixg = pt * 64 + wid * 16 + l16;
#pragma unroll
  for (int j = 0; j < 16; ++j) {
    const int k = (j >> 2) * 16 + q * 4 + (j & 3);
    float sa = sc[j] * inv;
    sc[j] = sa;
    saPb[((size_t)n * 64 + k) * 1024 + pixg] = (__bf16)(sa * rn);
  }
#pragma unroll
  for (int j = 0; j < 16; ++j) {
    float v = sc[j];
    v += __shfl_xor(v, 1);
    v += __shfl_xor(v, 2);
    v += __shfl_xor(v, 4);
    v += __shfl_xor(v, 8);
    sc[j] = v;
  }
  if (l16 == 0) {
#pragma unroll
    for (int j = 0; j < 16; ++j)
      atomicAdd(&Sl[(j >> 2) * 16 + q * 4 + (j & 3)], sc[j]);
  }
  __syncthreads();
  if (t < 64) atomicAdd(&S[n * 64 + t], Sl[t]);
}

// ---------------- VLAD aggregation: bf16 MFMA GEMM -------------------------
__global__ __launch_bounds__(256) void vlad_gemm(
    const __bf16* __restrict__ saPb, const __bf16* __restrict__ xeb,
    float* __restrict__ vpart) {
  __shared__ __align__(16) __bf16 Al[64 * 32];
  __shared__ __align__(16) __bf16 Bl[128 * 32];

  const int t = threadIdx.x;
  const int cT = blockIdx.x, n = blockIdx.y, ks = blockIdx.z;
  const int lane = t & 63, wid = t >> 6;
  const int l16 = lane & 15, q = lane >> 4;
  const int wrow = wid >> 1, wcol = wid & 1;

  const int ar = t >> 2, acp = t & 3;
  const __bf16* asrc = saPb + (size_t)n * 65536 + (size_t)ar * 1024 + ks * 256 +
                       (acp ^ ((ar >> 1) & 3)) * 8;
  const int br0 = t >> 2, bcp0 = t & 3;
  const int br1 = (t + 256) >> 2, bcp1 = t & 3;
  const __bf16* bsrc0 = xeb + (size_t)n * 524288 +
                        (size_t)(cT * 128 + br0) * 1024 + ks * 256 +
                        (bcp0 ^ ((br0 >> 1) & 3)) * 8;
  const __bf16* bsrc1 = xeb + (size_t)n * 524288 +
                        (size_t)(cT * 128 + br1) * 1024 + ks * 256 +
                        (bcp1 ^ ((br1 >> 1) & 3)) * 8;

  const int ldsb = wid * 512;
  const int sw = (q ^ ((l16 >> 1) & 3)) * 8;

  f32x4 acc[2][4];
#pragma unroll
  for (int i = 0; i < 2; ++i)
#pragma unroll
    for (int j = 0; j < 4; ++j) acc[i][j] = (f32x4){0.f, 0.f, 0.f, 0.f};

#pragma unroll 1
  for (int kc = 0; kc < 8; ++kc) {
    GLDS16(asrc + kc * 32, Al + ldsb);
    GLDS16(bsrc0 + kc * 32, Bl + ldsb);
    GLDS16(bsrc1 + kc * 32, Bl + 2048 + ldsb);
    __syncthreads();

    bf16x8 af[2], bf[4];
#pragma unroll
    for (int i = 0; i < 2; ++i)
      af[i] = *(const bf16x8*)&Al[(wrow * 32 + i * 16 + l16) * 32 + sw];
#pragma unroll
    for (int i = 0; i < 4; ++i)
      bf[i] = *(const bf16x8*)&Bl[(wcol * 64 + i * 16 + l16) * 32 + sw];
#pragma unroll
    for (int mt = 0; mt < 2; ++mt)
#pragma unroll
      for (int nt = 0; nt < 4; ++nt)
        acc[mt][nt] = __builtin_amdgcn_mfma_f32_16x16x32_bf16(
            af[mt], bf[nt], acc[mt][nt], 0, 0, 0);
    __syncthreads();
  }

  float* vp = vpart + (size_t)(ks * 16 + n) * 32768;
#pragma unroll
  for (int mt = 0; mt < 2; ++mt) {
    const int krow = wrow * 32 + mt * 16 + q * 4;
#pragma unroll
    for (int nt = 0; nt < 4; ++nt) {
      const int ccol = cT * 128 + wcol * 64 + nt * 16 + l16;
#pragma unroll
      for (int r = 0; r < 4; ++r)
        vp[(size_t)(krow + r) * 512 + ccol] = acc[mt][nt][r];
    }
  }
}

// ---------------- intra-norm (sums 4 K-split partials) ---------------------
__global__ __launch_bounds__(64) void intra_norm(float* __restrict__ vraw,
                                                 const float* __restrict__ vpart,
                                                 const float* __restrict__ S,
                                                 const float* __restrict__ cent,
                                                 float* __restrict__ gss) {
  const int b = blockIdx.x;  // n*64 + k
  const int n = b >> 6, k = b & 63;
  const int lane = threadIdx.x;
  const float s = S[b];
  float v[8];
  float ss = 0.f;
#pragma unroll
  for (int j = 0; j < 8; ++j) {
    const int c = lane * 8 + j;
    const size_t off = (size_t)b * 512 + c;
    float val = vpart[off] + vpart[524288 + off] + vpart[2 * 524288 + off] +
                vpart[3 * 524288 + off] - s * cent[k * 512 + c];
    v[j] = val;
    ss += val * val;
  }
#pragma unroll
  for (int off = 1; off < 64; off <<= 1) ss += __shfl_xor(ss, off);
  const float rn = 1.0f / fmaxf(sqrtf(ss), 1e-12f);
#pragma unroll
  for (int j = 0; j < 8; ++j) vraw[(size_t)b * 512 + lane * 8 + j] = v[j] * rn;
  if (lane == 0) atomicAdd(&gss[n], ss * rn * rn);
}

__global__ __launch_bounds__(256) void finalize(const float* __restrict__ vraw,
                                                const float* __restrict__ gss,
                                                float* __restrict__ out) {
  const int id = blockIdx.x * 256 + threadIdx.x;
  const int n = id >> 15;
  out[id] = vraw[id] * (1.0f / fmaxf(sqrtf(gss[n]), 1e-12f));
}

// ---------------- prep -----------------------------------------------------
// zero only the 132-pixel pad ring of xpad/hpad (interior fully overwritten)
__global__ __launch_bounds__(256) void zero_border(__bf16* __restrict__ xpad,
                                                   __bf16* __restrict__ hpad) {
  const int id = blockIdx.x * 256 + threadIdx.x;  // 0..135167
  const int n = id / 8448;
  const int rem = id - n * 8448;
  const int pb = rem >> 6;  // 0..131 border pixel
  const int c8 = rem & 63;
  int h, w;
  if (pb < 34) {
    h = 0;
    w = pb;
  } else if (pb < 68) {
    h = 33;
    w = pb - 34;
  } else {
    const int r2 = pb - 68;
    h = 1 + (r2 >> 1);
    w = (r2 & 1) * 33;
  }
  __bf16* base = blockIdx.y ? hpad : xpad;
  *(uint4*)(base + ((size_t)n * 1156 + h * 34 + w) * 512 + c8 * 8) =
      (uint4){0u, 0u, 0u, 0u};
}

// OIHW fp32 -> [o][kt*64 + p*8 + e] bf16, BK=64 XOR swizzle (p ^ (o&7)) baked
__global__ void wt_prep(const float* __restrict__ w1,
                        const float* __restrict__ w2, __bf16* __restrict__ wt1,
                        __bf16* __restrict__ wt2) {
  const int o = blockIdx.y;
  const int idk = blockIdx.x * 256 + threadIdx.x;  // 0..4607
  const float* w = blockIdx.z ? w2 : w1;
  __bf16* wt = blockIdx.z ? wt2 : wt1;
  const int kt = idk >> 6;  // 0..71
  const int p = (idk >> 3) & 7, e = idk & 7;
  const int logical = p ^ (o & 7);
  const int k2 = kt * 64 + logical * 8 + e;
  const int tap = k2 >> 9, ci = k2 & 511;
  wt[(size_t)o * 4608 + idk] = (__bf16)w[(size_t)o * 4608 + ci * 9 + tap];
}

__global__ void misc_prep(const float* g, const float* b, const float* m,
                          const float* v, const float* wA, float* scale,
                          float* shift, __bf16* watb, float* Sz) {
  const int i = blockIdx.x * 256 + threadIdx.x;
  if (i < 512) {
    float sc = g[i] / sqrtf(v[i] + 1e-5f);
    scale[i] = sc;
    shift[i] = b[i] - m[i] * sc;
  } else if (i < 512 + 32768) {
    const int id = i - 512;
    const int k = id >> 9, j = id & 511;
    const int kt = j >> 5, cpos = (j >> 3) & 3, e = j & 7;
    const int c = kt * 32 + (cpos ^ ((k >> 1) & 3)) * 8 + e;
    watb[(size_t)k * 512 + j] = (__bf16)wA[(size_t)k * 512 + c];
  } else if (i < 512 + 32768 + 1040) {
    Sz[i - (512 + 32768)] = 0.f;
  }
}

// ---------------------------------------------------------------------------
extern "C" void kernel_launch(void* const* d_in, const int* in_sizes, int n_in,
                              void* d_out, int out_size, void* d_ws,
                              size_t ws_size, hipStream_t stream) {
  const float* x = (const float*)d_in[0];
  const float* w1 = (const float*)d_in[1];
  const float* gam = (const float*)d_in[2];
  const float* bet = (const float*)d_in[3];
  const float* mean = (const float*)d_in[4];
  const float* var = (const float*)d_in[5];
  const float* w2 = (const float*)d_in[6];
  const float* wA = (const float*)d_in[7];
  const float* cent = (const float*)d_in[8];
  float* out = (float*)d_out;

  char* ws = (char*)d_ws;
  __bf16* Wt1 = (__bf16*)(ws + 0);          // 4,718,592 (dead after conv1)
  __bf16* Wt2 = (__bf16*)(ws + 4718592);    // 4,718,592 (dead after conv2)
  __bf16* xpad = (__bf16*)(ws + 9437184);   // 18,939,904 (dead after conv1)
  __bf16* xebT = (__bf16*)(ws + 9437184);   // alias: 16,777,216 (conv2 out)
  __bf16* saPb = (__bf16*)(ws + 26214400);  // 2,097,152
  __bf16* hpad = (__bf16*)(ws + 28377088);  // 18,939,904 (dead after conv2)
  __bf16* xeb = (__bf16*)(ws + 28377088);   // alias: 16,777,216 (expand out)
  float* vpart = (float*)(ws + 0);          // alias Wt1/2: 8,388,608
  float* vraw = (float*)(ws + 8388608);     // alias: 2,097,152
  float* scale = (float*)(ws + 47316992);   // 2048 B
  float* shift = (float*)(ws + 47319040);   // 2048 B
  __bf16* watb = (__bf16*)(ws + 47321088);  // 65,536 B
  float* S = (float*)(ws + 47386624);       // 4096 B
  float* gss = (float*)(ws + 47390720);     // 64 B

  float* xenc = out + 524288;  // output 1 (x_enc, fp32 NCHW)

  zero_border<<<dim3(528, 2), 256, 0, stream>>>(xpad, hpad);
  misc_prep<<<135, 256, 0, stream>>>(gam, bet, mean, var, wA, scale, shift,
                                     watb, S);
  wt_prep<<<dim3(18, 512, 2), 256, 0, stream>>>(w1, w2, Wt1, Wt2);
  xform<<<512, 256, 0, stream>>>(x, xpad);

  conv_gemm<0><<<dim3(128, 4), 256, 0, stream>>>(xpad, Wt1, scale, shift, hpad);
  conv_gemm<1><<<dim3(128, 4), 256, 0, stream>>>(hpad, Wt2, nullptr, nullptr,
                                                 xebT);

  expand_x<<<dim3(8, 16, 16), 256, 0, stream>>>(xebT, xenc, xeb);
  assign_softmax<<<dim3(16, 16), 256, 0, stream>>>(xebT, watb, saPb, S);
  vlad_gemm<<<dim3(4, 16, 4), 256, 0, stream>>>(saPb, xeb, vpart);
  intra_norm<<<1024, 64, 0, stream>>>(vraw, vpart, S, cent, gss);
  finalize<<<2048, 256, 0, stream>>>(vraw, gss, out);
}

// Round 6
// 319.675 us; speedup vs baseline: 4.8355x; 1.0783x over previous
//
#include <hip/hip_runtime.h>
#include <math.h>

// ---------------------------------------------------------------------------
// NetVLAD on gfx950.
// conv1/conv2: implicit GEMM, v_mfma_f32_16x16x32_bf16, 128x128 tile, BK=64.
//   NEW: halo-tiled P operand — per channel-chunk (64 ch) the block stages a
//   6x42x64 input halo into LDS ONCE and serves all 9 taps' B-fragments from
//   it (shifted ds_reads, XOR swizzle chunk = q ^ ((pcol+dw)&7); conflict-free
//   since row stride 2688 elem = 1344 dw = 42*32 ≡ 0 mod 32 banks).
//   W staged per (cchunk, tap): 16 KB, prepacked+swizzled (phys = log ^ (o&7)).
//   Cuts L2 staging traffic 2.36 MB -> 1.4 MB per block (~40%).
// conv2 emits xebT = bf16 [n][pix][c]; expand_x transposes to fp32 x_enc +
// bf16 xeb; assign_softmax + vlad are MFMA GEMMs (unchanged from R5).
// Fragment layouts (HW-verified): A/B: idx=lane&15, k=(lane>>4)*8+j;
// C/D: col=lane&15 (B idx), row=(lane>>4)*4+reg (A idx).
// ---------------------------------------------------------------------------

typedef __bf16 bf16x8 __attribute__((ext_vector_type(8)));
typedef float f32x4 __attribute__((ext_vector_type(4)));

#define GLDS16(gp, lp)                                                  \
  __builtin_amdgcn_global_load_lds(                                     \
      (const __attribute__((address_space(1))) void*)(gp),              \
      (__attribute__((address_space(3))) void*)(lp), 16, 0, 0)

// ---------------- conv as implicit GEMM, halo-tiled, BK=64 -----------------
// grid (128 pixel-tiles, 4 o-tiles), block 256 = 4 waves (2x2)
// MODE 0: BN+ReLU -> padded NHWC bf16 (hpad).
// MODE 1: xebT bf16 [n][pix][512] (c-contiguous), no BN.
template <int MODE>
__global__ __launch_bounds__(256) void conv_gemm(
    const __bf16* __restrict__ in,  // padded NHWC bf16 [16][34][34][512]
    const __bf16* __restrict__ wt,  // prepacked+swizzled [512][72*64]
    const float* __restrict__ scale, const float* __restrict__ shift,
    __bf16* __restrict__ outp) {
  __shared__ __align__(16) __bf16 Hl[6 * 42 * 64];  // 16128 elem, 31.5 KB
  __shared__ __align__(16) __bf16 Wl[128 * 64];     // 16 KB

  const int t = threadIdx.x;
  const int bx = blockIdx.x, oT = blockIdx.y;
  const int lane = t & 63, wid = t >> 6;
  const int l16 = lane & 15, q = lane >> 4;
  const int wrow = wid >> 1, wcol = wid & 1;

  const int n = bx >> 3;
  const int trow0 = (bx & 7) * 4;  // first pixel row of this 128-pixel tile

  // ---- W staging: 4 chunks/thread; Wl[row][phys8] = row*64 + phys*8
  const int swr = t >> 3, sp = t & 7;
  const __bf16* wsrc[4];
#pragma unroll
  for (int i = 0; i < 4; ++i)
    wsrc[i] = wt + (size_t)(oT * 128 + 32 * i + swr) * 4608 + sp * 8;

  // ---- halo staging: 8 chunks/thread over 6 rows x 42 cols x 8 c8-chunks
  const __bf16* inb = in + (size_t)n * (1156 * 512);
  const __bf16* hsrc[8];
  bool hval[8];
#pragma unroll
  for (int i = 0; i < 8; ++i) {
    const int jj = t + 256 * i;
    hval[i] = jj < 2016;
    const int hr = jj / 336;
    const int hrem = jj - hr * 336;
    const int hw = hrem >> 3, hc8 = hrem & 7;
    hsrc[i] = inb + ((size_t)((trow0 + hr) * 34 + hw)) * 512 +
              (hc8 ^ (hw & 7)) * 8;
  }

  // ---- fragment read constants
  const int c0 = (q ^ (l16 & 7)) * 8;
  const int c1 = ((4 + q) ^ (l16 & 7)) * 8;
  int aoff[4], prow_[4], pcol_[4];
#pragma unroll
  for (int i = 0; i < 4; ++i) {
    aoff[i] = (wrow * 64 + i * 16 + l16) * 64;
    const int p = wcol * 64 + i * 16 + l16;
    prow_[i] = p >> 5;
    pcol_[i] = p & 31;
  }

  f32x4 acc[4][4];
#pragma unroll
  for (int i = 0; i < 4; ++i)
#pragma unroll
    for (int j = 0; j < 4; ++j) acc[i][j] = (f32x4){0.f, 0.f, 0.f, 0.f};

#pragma unroll 1
  for (int cc = 0; cc < 8; ++cc) {
    // stage this c-chunk's halo (valid across all 9 taps)
#pragma unroll
    for (int i = 0; i < 8; ++i)
      if (hval[i]) GLDS16(hsrc[i] + cc * 64, Hl + (t + 256 * i) * 8);
#pragma unroll 1
    for (int tap = 0; tap < 9; ++tap) {
      // stage W[oc128][this tap, this c-chunk]
      const int woffs = (tap * 8 + cc) * 64;
#pragma unroll
      for (int i = 0; i < 4; ++i)
        GLDS16(wsrc[i] + woffs, Wl + (t + 256 * i) * 8);
      __syncthreads();

      const int dh = tap / 3, dw = tap - dh * 3;
      bf16x8 aw[4][2], bp[4][2];
#pragma unroll
      for (int i = 0; i < 4; ++i) {
        aw[i][0] = *(const bf16x8*)&Wl[aoff[i] + c0];
        aw[i][1] = *(const bf16x8*)&Wl[aoff[i] + c1];
      }
#pragma unroll
      for (int i = 0; i < 4; ++i) {
        const int col = pcol_[i] + dw;
        const int rb = (prow_[i] + dh) * 2688 + col * 64;
        const int xr = col & 7;
        bp[i][0] = *(const bf16x8*)&Hl[rb + (q ^ xr) * 8];
        bp[i][1] = *(const bf16x8*)&Hl[rb + ((4 + q) ^ xr) * 8];
      }
#pragma unroll
      for (int kh = 0; kh < 2; ++kh)
#pragma unroll
        for (int mt = 0; mt < 4; ++mt)
#pragma unroll
          for (int nt = 0; nt < 4; ++nt)
            acc[mt][nt] = __builtin_amdgcn_mfma_f32_16x16x32_bf16(
                aw[mt][kh], bp[nt][kh], acc[mt][nt], 0, 0, 0);
      __syncthreads();
    }
  }

  // ---- epilogue ----
#pragma unroll
  for (int nt = 0; nt < 4; ++nt) {
    const int m_l = wcol * 64 + nt * 16 + l16;
    const int mg2 = bx * 128 + m_l;
    const int n2 = mg2 >> 10, pix2 = mg2 & 1023;
#pragma unroll
    for (int mt = 0; mt < 4; ++mt) {
      const int ob = oT * 128 + wrow * 64 + mt * 16 + q * 4;
      f32x4 v = acc[mt][nt];
      union {
        __bf16 b[4];
        uint2 u;
      } pk;
      if (MODE == 0) {
        const f32x4 sc = *(const f32x4*)&scale[ob];
        const f32x4 sh = *(const f32x4*)&shift[ob];
#pragma unroll
        for (int r = 0; r < 4; ++r)
          pk.b[r] = (__bf16)fmaxf(v[r] * sc[r] + sh[r], 0.f);
        __bf16* dst = outp +
                      ((size_t)n2 * 1156 + ((pix2 >> 5) + 1) * 34 +
                       ((pix2 & 31) + 1)) * 512 + ob;
        *(uint2*)dst = pk.u;
      } else {
#pragma unroll
        for (int r = 0; r < 4; ++r) pk.b[r] = (__bf16)v[r];
        __bf16* dst = outp + ((size_t)n2 * 1024 + pix2) * 512 + ob;
        *(uint2*)dst = pk.u;
      }
    }
  }
}

// ---------------- x (fp32 NCHW) -> xpad (bf16 NHWC padded) -----------------
__global__ __launch_bounds__(256) void xform(const float* __restrict__ x,
                                             __bf16* __restrict__ xpad) {
  const int n = blockIdx.x >> 5, h = blockIdx.x & 31;
  const int t = threadIdx.x;
  const int w = t & 31, cg = t >> 5;
  const float* src = x + ((size_t)n * 512 + cg * 64) * 1024 + h * 32 + w;
  __bf16* dst =
      xpad + ((size_t)n * 1156 + (h + 1) * 34 + (w + 1)) * 512 + cg * 64;
  union {
    __bf16 b[8];
    uint4 u;
  } pk;
#pragma unroll 1
  for (int jj = 0; jj < 8; ++jj) {
#pragma unroll
    for (int j = 0; j < 8; ++j) pk.b[j] = (__bf16)src[(jj * 8 + j) * 1024];
    *(uint4*)(dst + jj * 8) = pk.u;
  }
}

// ---------------- expand: xebT [pix][c] -> xenc fp32 [c][pix] + xeb bf16 ---
__global__ __launch_bounds__(256) void expand_x(const __bf16* __restrict__ xebT,
                                                float* __restrict__ xenc,
                                                __bf16* __restrict__ xeb) {
  __shared__ __align__(16) __bf16 Ll[64 * 64];
  const int t = threadIdx.x;
  const int cc = blockIdx.x, ptile = blockIdx.y, n = blockIdx.z;
  const int p0 = ptile * 64, c0 = cc * 64;
#pragma unroll
  for (int i = 0; i < 2; ++i) {
    const int u = t * 2 + i;
    const int pix = u >> 3, c8 = u & 7;
    uint4 v =
        *(const uint4*)&xebT[((size_t)n * 1024 + p0 + pix) * 512 + c0 + c8 * 8];
    *(uint4*)&Ll[pix * 64 + (c8 ^ (pix & 7)) * 8] = v;
  }
  __syncthreads();
  const int c = t >> 2, g = t & 3;
  union {
    float f[4];
    float4 v;
  } fv[4];
  union {
    __bf16 b[16];
    uint4 u[2];
  } bv;
#pragma unroll
  for (int r = 0; r < 16; ++r) {
    const int pix = g * 16 + r;
    __bf16 b = Ll[pix * 64 + ((c >> 3) ^ (pix & 7)) * 8 + (c & 7)];
    bv.b[r] = b;
    fv[r >> 2].f[r & 3] = (float)b;
  }
  float* fd = xenc + ((size_t)n * 512 + c0 + c) * 1024 + p0 + g * 16;
#pragma unroll
  for (int r = 0; r < 4; ++r) *(float4*)(fd + r * 4) = fv[r].v;
  __bf16* bd = xeb + ((size_t)n * 512 + c0 + c) * 1024 + p0 + g * 16;
  *(uint4*)bd = bv.u[0];
  *(uint4*)(bd + 8) = bv.u[1];
}

// ---------------- soft-assign + softmax (MFMA) -----------------------------
__global__ __launch_bounds__(256) void assign_softmax(
    const __bf16* __restrict__ xebT, const __bf16* __restrict__ watb,
    __bf16* __restrict__ saPb, float* __restrict__ S) {
  __shared__ __align__(16) __bf16 Al[64 * 32];
  __shared__ __align__(16) __bf16 Wlb[64 * 32];
  __shared__ float Sl[64];
  const int t = threadIdx.x;
  const int pt = blockIdx.x, n = blockIdx.y;
  const int lane = t & 63, wid = t >> 6;
  const int l16 = lane & 15, q = lane >> 4;
  if (t < 64) Sl[t] = 0.f;

  const int arow = t >> 2;  // pixel row 0..63
  const __bf16* asrc = xebT + ((size_t)n * 1024 + pt * 64 + arow) * 512 +
                       ((t & 3) ^ ((arow >> 1) & 3)) * 8;
  const __bf16* wsrc = watb + (size_t)(t >> 2) * 512 + (t & 3) * 8;
  const int ldsb = wid * 512;
  const int sw = (q ^ ((l16 >> 1) & 3)) * 8;
  const int pnoff = (t >> 2) * 32 + (t & 3) * 8;

  f32x4 acc[4];
#pragma unroll
  for (int i = 0; i < 4; ++i) acc[i] = (f32x4){0.f, 0.f, 0.f, 0.f};
  float pn = 0.f;

#pragma unroll 1
  for (int kc = 0; kc < 16; ++kc) {
    GLDS16(asrc + kc * 32, Al + ldsb);
    GLDS16(wsrc + kc * 32, Wlb + ldsb);
    __syncthreads();
    {
      bf16x8 v = *(const bf16x8*)&Al[pnoff];
#pragma unroll
      for (int j = 0; j < 8; ++j) {
        float f = (float)v[j];
        pn = fmaf(f, f, pn);
      }
    }
    bf16x8 pf = *(const bf16x8*)&Al[(wid * 16 + l16) * 32 + sw];
    bf16x8 wf[4];
#pragma unroll
    for (int ka = 0; ka < 4; ++ka)
      wf[ka] = *(const bf16x8*)&Wlb[(ka * 16 + l16) * 32 + sw];
#pragma unroll
    for (int ka = 0; ka < 4; ++ka)
      acc[ka] =
          __builtin_amdgcn_mfma_f32_16x16x32_bf16(wf[ka], pf, acc[ka], 0, 0, 0);
    __syncthreads();
  }
  pn += __shfl_xor(pn, 1);
  pn += __shfl_xor(pn, 2);
  const float rn = 1.0f / fmaxf(sqrtf(__shfl(pn, l16 * 4)), 1e-12f);

  float sc[16];
  float m = -3.4e38f;
#pragma unroll
  for (int ka = 0; ka < 4; ++ka)
#pragma unroll
    for (int r = 0; r < 4; ++r) {
      float v = acc[ka][r] * rn;
      sc[ka * 4 + r] = v;
      m = fmaxf(m, v);
    }
  m = fmaxf(m, __shfl_xor(m, 16));
  m = fmaxf(m, __shfl_xor(m, 32));
  float s = 0.f;
#pragma unroll
  for (int j = 0; j < 16; ++j) {
    sc[j] = __expf(sc[j] - m);
    s += sc[j];
  }
  s += __shfl_xor(s, 16);
  s += __shfl_xor(s, 32);
  const float inv = 1.0f / s;
  const int pixg = pt * 64 + wid * 16 + l16;
#pragma unroll
  for (int j = 0; j < 16; ++j) {
    const int k = (j >> 2) * 16 + q * 4 + (j & 3);
    float sa = sc[j] * inv;
    sc[j] = sa;
    saPb[((size_t)n * 64 + k) * 1024 + pixg] = (__bf16)(sa * rn);
  }
#pragma unroll
  for (int j = 0; j < 16; ++j) {
    float v = sc[j];
    v += __shfl_xor(v, 1);
    v += __shfl_xor(v, 2);
    v += __shfl_xor(v, 4);
    v += __shfl_xor(v, 8);
    sc[j] = v;
  }
  if (l16 == 0) {
#pragma unroll
    for (int j = 0; j < 16; ++j)
      atomicAdd(&Sl[(j >> 2) * 16 + q * 4 + (j & 3)], sc[j]);
  }
  __syncthreads();
  if (t < 64) atomicAdd(&S[n * 64 + t], Sl[t]);
}

// ---------------- VLAD aggregation: bf16 MFMA GEMM -------------------------
__global__ __launch_bounds__(256) void vlad_gemm(
    const __bf16* __restrict__ saPb, const __bf16* __restrict__ xeb,
    float* __restrict__ vpart) {
  __shared__ __align__(16) __bf16 Al[64 * 32];
  __shared__ __align__(16) __bf16 Bl[128 * 32];

  const int t = threadIdx.x;
  const int cT = blockIdx.x, n = blockIdx.y, ks = blockIdx.z;
  const int lane = t & 63, wid = t >> 6;
  const int l16 = lane & 15, q = lane >> 4;
  const int wrow = wid >> 1, wcol = wid & 1;

  const int ar = t >> 2, acp = t & 3;
  const __bf16* asrc = saPb + (size_t)n * 65536 + (size_t)ar * 1024 + ks * 256 +
                       (acp ^ ((ar >> 1) & 3)) * 8;
  const int br0 = t >> 2, bcp0 = t & 3;
  const int br1 = (t + 256) >> 2, bcp1 = t & 3;
  const __bf16* bsrc0 = xeb + (size_t)n * 524288 +
                        (size_t)(cT * 128 + br0) * 1024 + ks * 256 +
                        (bcp0 ^ ((br0 >> 1) & 3)) * 8;
  const __bf16* bsrc1 = xeb + (size_t)n * 524288 +
                        (size_t)(cT * 128 + br1) * 1024 + ks * 256 +
                        (bcp1 ^ ((br1 >> 1) & 3)) * 8;

  const int ldsb = wid * 512;
  const int sw = (q ^ ((l16 >> 1) & 3)) * 8;

  f32x4 acc[2][4];
#pragma unroll
  for (int i = 0; i < 2; ++i)
#pragma unroll
    for (int j = 0; j < 4; ++j) acc[i][j] = (f32x4){0.f, 0.f, 0.f, 0.f};

#pragma unroll 1
  for (int kc = 0; kc < 8; ++kc) {
    GLDS16(asrc + kc * 32, Al + ldsb);
    GLDS16(bsrc0 + kc * 32, Bl + ldsb);
    GLDS16(bsrc1 + kc * 32, Bl + 2048 + ldsb);
    __syncthreads();

    bf16x8 af[2], bf[4];
#pragma unroll
    for (int i = 0; i < 2; ++i)
      af[i] = *(const bf16x8*)&Al[(wrow * 32 + i * 16 + l16) * 32 + sw];
#pragma unroll
    for (int i = 0; i < 4; ++i)
      bf[i] = *(const bf16x8*)&Bl[(wcol * 64 + i * 16 + l16) * 32 + sw];
#pragma unroll
    for (int mt = 0; mt < 2; ++mt)
#pragma unroll
      for (int nt = 0; nt < 4; ++nt)
        acc[mt][nt] = __builtin_amdgcn_mfma_f32_16x16x32_bf16(
            af[mt], bf[nt], acc[mt][nt], 0, 0, 0);
    __syncthreads();
  }

  float* vp = vpart + (size_t)(ks * 16 + n) * 32768;
#pragma unroll
  for (int mt = 0; mt < 2; ++mt) {
    const int krow = wrow * 32 + mt * 16 + q * 4;
#pragma unroll
    for (int nt = 0; nt < 4; ++nt) {
      const int ccol = cT * 128 + wcol * 64 + nt * 16 + l16;
#pragma unroll
      for (int r = 0; r < 4; ++r)
        vp[(size_t)(krow + r) * 512 + ccol] = acc[mt][nt][r];
    }
  }
}

// ---------------- intra-norm (sums 4 K-split partials) ---------------------
__global__ __launch_bounds__(64) void intra_norm(float* __restrict__ vraw,
                                                 const float* __restrict__ vpart,
                                                 const float* __restrict__ S,
                                                 const float* __restrict__ cent,
                                                 float* __restrict__ gss) {
  const int b = blockIdx.x;  // n*64 + k
  const int n = b >> 6, k = b & 63;
  const int lane = threadIdx.x;
  const float s = S[b];
  float v[8];
  float ss = 0.f;
#pragma unroll
  for (int j = 0; j < 8; ++j) {
    const int c = lane * 8 + j;
    const size_t off = (size_t)b * 512 + c;
    float val = vpart[off] + vpart[524288 + off] + vpart[2 * 524288 + off] +
                vpart[3 * 524288 + off] - s * cent[k * 512 + c];
    v[j] = val;
    ss += val * val;
  }
#pragma unroll
  for (int off = 1; off < 64; off <<= 1) ss += __shfl_xor(ss, off);
  const float rn = 1.0f / fmaxf(sqrtf(ss), 1e-12f);
#pragma unroll
  for (int j = 0; j < 8; ++j) vraw[(size_t)b * 512 + lane * 8 + j] = v[j] * rn;
  if (lane == 0) atomicAdd(&gss[n], ss * rn * rn);
}

__global__ __launch_bounds__(256) void finalize(const float* __restrict__ vraw,
                                                const float* __restrict__ gss,
                                                float* __restrict__ out) {
  const int id = blockIdx.x * 256 + threadIdx.x;
  const int n = id >> 15;
  out[id] = vraw[id] * (1.0f / fmaxf(sqrtf(gss[n]), 1e-12f));
}

// ---------------- prep -----------------------------------------------------
// zero only the 132-pixel pad ring of xpad/hpad (interior fully overwritten)
__global__ __launch_bounds__(256) void zero_border(__bf16* __restrict__ xpad,
                                                   __bf16* __restrict__ hpad) {
  const int id = blockIdx.x * 256 + threadIdx.x;  // 0..135167
  const int n = id / 8448;
  const int rem = id - n * 8448;
  const int pb = rem >> 6;  // 0..131 border pixel
  const int c8 = rem & 63;
  int h, w;
  if (pb < 34) {
    h = 0;
    w = pb;
  } else if (pb < 68) {
    h = 33;
    w = pb - 34;
  } else {
    const int r2 = pb - 68;
    h = 1 + (r2 >> 1);
    w = (r2 & 1) * 33;
  }
  __bf16* base = blockIdx.y ? hpad : xpad;
  *(uint4*)(base + ((size_t)n * 1156 + h * 34 + w) * 512 + c8 * 8) =
      (uint4){0u, 0u, 0u, 0u};
}

// OIHW fp32 -> [o][kt*64 + p*8 + e] bf16, BK=64 XOR swizzle (p ^ (o&7)) baked.
// Coalesced: stage the 4608 contiguous fp32 of one o into LDS, gather there.
__global__ __launch_bounds__(256) void wt_prep(const float* __restrict__ w1,
                                               const float* __restrict__ w2,
                                               __bf16* __restrict__ wt1,
                                               __bf16* __restrict__ wt2) {
  __shared__ float Lw[4608];
  const int o = blockIdx.x;
  const float* w = blockIdx.y ? w2 : w1;
  __bf16* wt = blockIdx.y ? wt2 : wt1;
  const int t = threadIdx.x;
#pragma unroll
  for (int i = 0; i < 18; ++i)
    Lw[t + 256 * i] = w[(size_t)o * 4608 + t + 256 * i];
  __syncthreads();
#pragma unroll
  for (int i = 0; i < 18; ++i) {
    const int idk = t + 256 * i;
    const int kt = idk >> 6;
    const int p = (idk >> 3) & 7, e = idk & 7;
    const int logical = p ^ (o & 7);
    const int k2 = kt * 64 + logical * 8 + e;
    const int tap = k2 >> 9, ci = k2 & 511;
    wt[(size_t)o * 4608 + idk] = (__bf16)Lw[ci * 9 + tap];
  }
}

__global__ void misc_prep(const float* g, const float* b, const float* m,
                          const float* v, const float* wA, float* scale,
                          float* shift, __bf16* watb, float* Sz) {
  const int i = blockIdx.x * 256 + threadIdx.x;
  if (i < 512) {
    float sc = g[i] / sqrtf(v[i] + 1e-5f);
    scale[i] = sc;
    shift[i] = b[i] - m[i] * sc;
  } else if (i < 512 + 32768) {
    const int id = i - 512;
    const int k = id >> 9, j = id & 511;
    const int kt = j >> 5, cpos = (j >> 3) & 3, e = j & 7;
    const int c = kt * 32 + (cpos ^ ((k >> 1) & 3)) * 8 + e;
    watb[(size_t)k * 512 + j] = (__bf16)wA[(size_t)k * 512 + c];
  } else if (i < 512 + 32768 + 1040) {
    Sz[i - (512 + 32768)] = 0.f;
  }
}

// ---------------------------------------------------------------------------
extern "C" void kernel_launch(void* const* d_in, const int* in_sizes, int n_in,
                              void* d_out, int out_size, void* d_ws,
                              size_t ws_size, hipStream_t stream) {
  const float* x = (const float*)d_in[0];
  const float* w1 = (const float*)d_in[1];
  const float* gam = (const float*)d_in[2];
  const float* bet = (const float*)d_in[3];
  const float* mean = (const float*)d_in[4];
  const float* var = (const float*)d_in[5];
  const float* w2 = (const float*)d_in[6];
  const float* wA = (const float*)d_in[7];
  const float* cent = (const float*)d_in[8];
  float* out = (float*)d_out;

  char* ws = (char*)d_ws;
  __bf16* Wt1 = (__bf16*)(ws + 0);          // 4,718,592 (dead after conv1)
  __bf16* Wt2 = (__bf16*)(ws + 4718592);    // 4,718,592 (dead after conv2)
  __bf16* xpad = (__bf16*)(ws + 9437184);   // 18,939,904 (dead after conv1)
  __bf16* xebT = (__bf16*)(ws + 9437184);   // alias: 16,777,216 (conv2 out)
  __bf16* saPb = (__bf16*)(ws + 26214400);  // 2,097,152
  __bf16* hpad = (__bf16*)(ws + 28377088);  // 18,939,904 (dead after conv2)
  __bf16* xeb = (__bf16*)(ws + 28377088);   // alias: 16,777,216 (expand out)
  float* vpart = (float*)(ws + 0);          // alias Wt1/2: 8,388,608
  float* vraw = (float*)(ws + 8388608);     // alias: 2,097,152
  float* scale = (float*)(ws + 47316992);   // 2048 B
  float* shift = (float*)(ws + 47319040);   // 2048 B
  __bf16* watb = (__bf16*)(ws + 47321088);  // 65,536 B
  float* S = (float*)(ws + 47386624);       // 4096 B
  float* gss = (float*)(ws + 47390720);     // 64 B

  float* xenc = out + 524288;  // output 1 (x_enc, fp32 NCHW)

  zero_border<<<dim3(528, 2), 256, 0, stream>>>(xpad, hpad);
  misc_prep<<<135, 256, 0, stream>>>(gam, bet, mean, var, wA, scale, shift,
                                     watb, S);
  wt_prep<<<dim3(512, 2), 256, 0, stream>>>(w1, w2, Wt1, Wt2);
  xform<<<512, 256, 0, stream>>>(x, xpad);

  conv_gemm<0><<<dim3(128, 4), 256, 0, stream>>>(xpad, Wt1, scale, shift, hpad);
  conv_gemm<1><<<dim3(128, 4), 256, 0, stream>>>(hpad, Wt2, nullptr, nullptr,
                                                 xebT);

  expand_x<<<dim3(8, 16, 16), 256, 0, stream>>>(xebT, xenc, xeb);
  assign_softmax<<<dim3(16, 16), 256, 0, stream>>>(xebT, watb, saPb, S);
  vlad_gemm<<<dim3(4, 16, 4), 256, 0, stream>>>(saPb, xeb, vpart);
  intra_norm<<<1024, 64, 0, stream>>>(vraw, vpart, S, cent, gss);
  finalize<<<2048, 256, 0, stream>>>(vraw, gss, out);
}